// Round 1
// baseline (658.924 us; speedup 1.0000x reference)
//
#include <hip/hip_runtime.h>
#include <stdint.h>
#include <stddef.h>

// ---------------------------------------------------------------------------
// SimpleRNN (gated linear attention) — chunked parallel formulation.
//   q = hs@Wq^T+bq ; k = sig(hs@Wk^T+bk) ; g = sig(hs@Wg^T+bg) ; v = hs@Wv^T+bv
//   S_t = diag(g_t) S_{t-1} + k_t v_t^T ; out_t = q_t S_t ; y = out@Wo^T+bo
// Chunked (C=64): la = within-chunk inclusive cumsum(log g)
//   q~ = q*exp(la), k~ = k*exp(-la), kbar = k*exp(laC-la)
//   out = tril(q~ k~^T) V  +  q~ @ S_prev
//   U_c = kbar^T V ;  S_c = exp(laC) (.) S_{c-1} + U_c   (elementwise scan)
// ---------------------------------------------------------------------------

#define DEVI __device__ __forceinline__

typedef __bf16 bf16;
typedef __bf16 bf16x8 __attribute__((ext_vector_type(8)));
typedef __bf16 bf16x4 __attribute__((ext_vector_type(4)));
typedef float  f32x4  __attribute__((ext_vector_type(4)));

static constexpr int T_  = 4096;
static constexpr int H_  = 2048;
static constexpr int KD  = 1024;
static constexpr int VD  = 1024;
static constexpr int OD  = 2048;
static constexpr int CH  = 64;                 // chunk length
static constexpr int NCHUNK = T_ / CH;         // 64
static constexpr int NGROUP = 2;               // chunk groups (ws economy)
static constexpr int CPG    = NCHUNK / NGROUP; // 32

DEVI bf16 tobf(float f) {
  union { float f; uint32_t u; } x; x.f = f;
  uint32_t r = (x.u + 0x7FFFu + ((x.u >> 16) & 1u)) >> 16;  // RNE
  union { uint16_t s; bf16 b; } y; y.s = (uint16_t)r;
  return y.b;
}

DEVI f32x4 fzero() { f32x4 z = {0.f, 0.f, 0.f, 0.f}; return z; }

// async global->LDS, 16B per lane. LDS dest is wave-uniform base + lane*16;
// we pass the per-lane pointer (lane-linear layout) — first lane = wave base.
DEVI void gld16(const bf16* g, bf16* l) {
  auto* g1 = reinterpret_cast<__attribute__((address_space(1))) uint32_t*>(
      (uintptr_t)g);
  auto* l3 = reinterpret_cast<__attribute__((address_space(3))) uint32_t*>(
      (uintptr_t)l);
  __builtin_amdgcn_global_load_lds(g1, l3, 16, 0, 0);
}

// C[m0+..BM, n0+..BN] += A[M,K] * B[N,K]^T, both row-major K-contiguous.
// 4 waves in 2x2 grid; per wave MR x NR 16x16 fragments; BK=32 (m97 pattern).
template<int BM, int BN>
DEVI void gemm_core(const bf16* A, int lda, int m0,
                    const bf16* B, int ldb, int n0,
                    int K, f32x4* acc, bf16* sA, bf16* sB, int tid)
{
  constexpr int MR = BM / 32;
  constexpr int NR = BN / 32;
  const int lane = tid & 63;
  const int wr = (tid >> 6) >> 1;
  const int wc = (tid >> 6) & 1;
  const int srow = tid >> 2;          // staging row within 64-row round
  const int skof = (tid & 3) * 8;     // staging k-offset (8 bf16 = 16B)
  for (int k0 = 0; k0 < K; k0 += 32) {
    __syncthreads();
#pragma unroll
    for (int r = 0; r < BM / 64; ++r)
      gld16(A + (size_t)(m0 + r * 64 + srow) * lda + k0 + skof,
            sA + r * 2048 + tid * 8);
#pragma unroll
    for (int r = 0; r < BN / 64; ++r)
      gld16(B + (size_t)(n0 + r * 64 + srow) * ldb + k0 + skof,
            sB + r * 2048 + tid * 8);
    __syncthreads();   // compiler drains vmcnt(0) before s_barrier
    bf16x8 af[MR], bfr[NR];
#pragma unroll
    for (int m = 0; m < MR; ++m)
      af[m] = *(const bf16x8*)(sA + (wr * (MR * 16) + m * 16 + (lane & 15)) * 32
                               + (lane >> 4) * 8);
#pragma unroll
    for (int n = 0; n < NR; ++n)
      bfr[n] = *(const bf16x8*)(sB + (wc * (NR * 16) + n * 16 + (lane & 15)) * 32
                                + (lane >> 4) * 8);
#pragma unroll
    for (int m = 0; m < MR; ++m)
#pragma unroll
      for (int n = 0; n < NR; ++n)
        acc[m * NR + n] = __builtin_amdgcn_mfma_f32_16x16x32_bf16(
            af[m], bfr[n], acc[m * NR + n], 0, 0, 0);
  }
}

// ---------------------------------------------------------------------------
__global__ __launch_bounds__(256) void k_cvt(const float* __restrict__ in,
                                             bf16* __restrict__ out, int n) {
  int i = (blockIdx.x * 256 + threadIdx.x) * 4;
  if (i >= n) return;
  float4 v = *(const float4*)(in + i);
  bf16x4 o; o[0] = tobf(v.x); o[1] = tobf(v.y); o[2] = tobf(v.z); o[3] = tobf(v.w);
  *(bf16x4*)(out + i) = o;
}

// Projections: N = [q(1024) | k | g | v]; per-segment epilogue.
__global__ __launch_bounds__(256) void k_proj(
    const bf16* __restrict__ hsb,
    const bf16* __restrict__ Wqb, const bf16* __restrict__ Wkb,
    const bf16* __restrict__ Wgb, const bf16* __restrict__ Wvb,
    const float* __restrict__ bq, const float* __restrict__ bk,
    const float* __restrict__ bg, const float* __restrict__ bv,
    bf16* __restrict__ qb, bf16* __restrict__ kb,
    float* __restrict__ la, bf16* __restrict__ vb)
{
  __shared__ __align__(16) bf16 sA[128 * 32];
  __shared__ __align__(16) bf16 sB[128 * 32];
  const int m0 = blockIdx.x * 128;
  const int nseg = blockIdx.y;          // 0..31
  const int seg = nseg >> 3;            // 0..3
  const int n0 = (nseg & 7) * 128;      // within segment
  const bf16* W = seg == 0 ? Wqb : seg == 1 ? Wkb : seg == 2 ? Wgb : Wvb;
  const float* bias = seg == 0 ? bq : seg == 1 ? bk : seg == 2 ? bg : bv;
  const int tid = threadIdx.x, lane = tid & 63;
  const int wr = (tid >> 6) >> 1, wc = (tid >> 6) & 1;
  f32x4 acc[16];
#pragma unroll
  for (int i = 0; i < 16; ++i) acc[i] = fzero();
  gemm_core<128, 128>(hsb, H_, m0, W, H_, n0, H_, acc, sA, sB, tid);
#pragma unroll
  for (int m = 0; m < 4; ++m)
#pragma unroll
    for (int n = 0; n < 4; ++n) {
      f32x4 v = acc[m * 4 + n];
      int col = n0 + wc * 64 + n * 16 + (lane & 15);
      float b = bias[col];
#pragma unroll
      for (int r = 0; r < 4; ++r) {
        int row = m0 + wr * 64 + m * 16 + (lane >> 4) * 4 + r;
        float x = v[r] + b;
        size_t o = (size_t)row * KD + col;
        if (seg == 0)      qb[o] = tobf(x);
        else if (seg == 1) kb[o] = tobf(1.f / (1.f + expf(-x)));
        else if (seg == 2) la[o] = fminf(x, 0.f) - log1pf(expf(-fabsf(x)));
        else               vb[o] = tobf(x);
      }
    }
}

// within-chunk inclusive cumsum of log g (in place)
__global__ __launch_bounds__(256) void k_cumsum(float* __restrict__ la) {
  int gid = blockIdx.x * 256 + threadIdx.x;
  int c = gid >> 10, kk = gid & 1023;
  size_t base = (size_t)c * CH * KD + kk;
  float s = 0.f;
  for (int i = 0; i < CH; ++i) {
    s += la[base + (size_t)i * KD];
    la[base + (size_t)i * KD] = s;
  }
}

// q~,k~ (t-major) ; kbar^T [c][kk][t] ; V^T [c][vv][t]
__global__ __launch_bounds__(256) void k_transform(
    const bf16* __restrict__ qb, const bf16* __restrict__ kb,
    const float* __restrict__ la, const bf16* __restrict__ vb,
    bf16* __restrict__ qt, bf16* __restrict__ kt,
    bf16* __restrict__ kbarT, bf16* __restrict__ vT)
{
  __shared__ bf16 tr[64][72];
  const int c = blockIdx.y, tile = blockIdx.x, path = blockIdx.z;
  const int tid = threadIdx.x;
  const int colL = tid & 63;
  const int rbase = tid >> 6;
  if (path == 0) {
    const int kk0 = tile * 64;
    const int kk = kk0 + colL;
    const float lc = la[(size_t)(c * CH + 63) * KD + kk];
#pragma unroll
    for (int i = 0; i < 16; ++i) {
      int tl = rbase + 4 * i;
      size_t idx = (size_t)(c * CH + tl) * KD + kk;
      float lav = la[idx];
      float qv = (float)qb[idx];
      float kv = (float)kb[idx];
      qt[idx] = tobf(qv * expf(lav));
      kt[idx] = tobf(kv * expf(-lav));
      tr[colL][tl] = tobf(kv * expf(lc - lav));   // kbar, staged for transpose
    }
    __syncthreads();
#pragma unroll
    for (int i = 0; i < 16; ++i) {
      int row = rbase + 4 * i;
      kbarT[((size_t)c * KD + kk0 + row) * 64 + colL] = tr[row][colL];
    }
  } else {
    const int vv0 = tile * 64;
#pragma unroll
    for (int i = 0; i < 16; ++i) {
      int tl = rbase + 4 * i;
      tr[colL][tl] = vb[(size_t)(c * CH + tl) * VD + vv0 + colL];
    }
    __syncthreads();
#pragma unroll
    for (int i = 0; i < 16; ++i) {
      int row = rbase + 4 * i;
      vT[((size_t)c * VD + vv0 + row) * 64 + colL] = tr[row][colL];
    }
  }
}

// intra-chunk: P = tril(q~ k~^T) (64x64), out_intra = P @ V -> attn (fp32)
__global__ __launch_bounds__(256) void k_intra(
    const bf16* __restrict__ qt, const bf16* __restrict__ kt,
    const bf16* __restrict__ vT, float* __restrict__ attn)
{
  __shared__ __align__(16) bf16 sA[64 * 32];
  __shared__ __align__(16) bf16 sB[64 * 32];
  __shared__ __align__(16) bf16 sV[128 * 72];   // padded V^T slice
  __shared__ __align__(16) bf16 Pl[64 * 72];    // padded P
  const int c = blockIdx.x;
  const int tid = threadIdx.x, lane = tid & 63;
  const int wr = (tid >> 6) >> 1, wc = (tid >> 6) & 1;
  f32x4 acc[4];
#pragma unroll
  for (int i = 0; i < 4; ++i) acc[i] = fzero();
  gemm_core<64, 64>(qt + (size_t)c * CH * KD, KD, 0,
                    kt + (size_t)c * CH * KD, KD, 0, KD, acc, sA, sB, tid);
  // mask (j<=t) and store P as bf16
#pragma unroll
  for (int m = 0; m < 2; ++m)
#pragma unroll
    for (int n = 0; n < 2; ++n) {
      f32x4 v = acc[m * 2 + n];
      int j = wc * 32 + n * 16 + (lane & 15);
#pragma unroll
      for (int r = 0; r < 4; ++r) {
        int t = wr * 32 + m * 16 + (lane >> 4) * 4 + r;
        Pl[t * 72 + j] = (j <= t) ? tobf(v[r]) : tobf(0.f);
      }
    }
  for (int nb = 0; nb < 8; ++nb) {
    __syncthreads();
    // stage V^T rows [nb*128, nb*128+128), padded stride 72
#pragma unroll
    for (int rr = 0; rr < 4; ++rr) {
      int row = rr * 32 + (tid >> 3);
      int j0 = (tid & 7) * 8;
      bf16x8 vv = *(const bf16x8*)(vT + ((size_t)c * VD + nb * 128 + row) * 64 + j0);
      *(bf16x8*)(sV + row * 72 + j0) = vv;
    }
    __syncthreads();
    f32x4 a2[8];
#pragma unroll
    for (int i = 0; i < 8; ++i) a2[i] = fzero();
#pragma unroll
    for (int ks = 0; ks < 64; ks += 32) {
      bf16x8 af[2], bfr[4];
#pragma unroll
      for (int m = 0; m < 2; ++m)
        af[m] = *(const bf16x8*)(Pl + (wr * 32 + m * 16 + (lane & 15)) * 72
                                 + ks + (lane >> 4) * 8);
#pragma unroll
      for (int n = 0; n < 4; ++n)
        bfr[n] = *(const bf16x8*)(sV + (wc * 64 + n * 16 + (lane & 15)) * 72
                                  + ks + (lane >> 4) * 8);
#pragma unroll
      for (int m = 0; m < 2; ++m)
#pragma unroll
        for (int n = 0; n < 4; ++n)
          a2[m * 4 + n] = __builtin_amdgcn_mfma_f32_16x16x32_bf16(
              af[m], bfr[n], a2[m * 4 + n], 0, 0, 0);
    }
#pragma unroll
    for (int m = 0; m < 2; ++m)
#pragma unroll
      for (int n = 0; n < 4; ++n) {
        int col = wc * 64 + n * 16 + (lane & 15);
#pragma unroll
        for (int r = 0; r < 4; ++r) {
          int row = wr * 32 + m * 16 + (lane >> 4) * 4 + r;
          attn[((size_t)c * CH + row) * VD + nb * 128 + col] = a2[m * 4 + n][r];
        }
      }
  }
}

// U^T[vv][kk] = sum_j V[j,vv] kbar[j,kk]  -> ustore slot (bf16)
__global__ __launch_bounds__(256) void k_ugemm(
    const bf16* __restrict__ vT, const bf16* __restrict__ kbarT,
    bf16* __restrict__ ustore, int g)
{
  __shared__ __align__(16) bf16 sA[128 * 32];
  __shared__ __align__(16) bf16 sB[128 * 32];
  const int cl = blockIdx.z, c = g * CPG + cl;
  const int m0 = blockIdx.x * 128, n0 = blockIdx.y * 128;
  const int tid = threadIdx.x, lane = tid & 63;
  const int wr = (tid >> 6) >> 1, wc = (tid >> 6) & 1;
  f32x4 acc[16];
#pragma unroll
  for (int i = 0; i < 16; ++i) acc[i] = fzero();
  gemm_core<128, 128>(vT + (size_t)c * VD * 64, 64, m0,
                      kbarT + (size_t)c * KD * 64, 64, n0, 64, acc, sA, sB, tid);
  bf16* dst = ustore + (size_t)cl * KD * VD;
#pragma unroll
  for (int m = 0; m < 4; ++m)
#pragma unroll
    for (int n = 0; n < 4; ++n) {
      f32x4 v = acc[m * 4 + n];
      int col = wc * 64 + n * 16 + (lane & 15);
#pragma unroll
      for (int r = 0; r < 4; ++r) {
        int row = wr * 64 + m * 16 + (lane >> 4) * 4 + r;
        dst[(size_t)(m0 + row) * KD + n0 + col] = tobf(v[r]);
      }
    }
}

// elementwise scan over chunks (in place: slot c becomes state AFTER chunk c)
__global__ __launch_bounds__(256) void k_scan(
    bf16* __restrict__ ustore, const float* __restrict__ la,
    float* __restrict__ Sinit, bf16* __restrict__ ScarryB,
    float* __restrict__ dstate, int g)
{
  __shared__ float tl[64][65];
  const int vv0 = blockIdx.x * 64, kk0 = blockIdx.y * 64;
  const int tid = threadIdx.x;
  const int col = tid & 63;       // kk local
  const int r0 = tid >> 6;        // 0..3 (vv local base)
  const int kk = kk0 + col;
  float s[16];
  if (g == 0) {
#pragma unroll
    for (int i = 0; i < 16; ++i) s[i] = 0.f;
  } else {
#pragma unroll
    for (int i = 0; i < 16; ++i)
      s[i] = Sinit[(size_t)(vv0 + r0 + 4 * i) * KD + kk];
  }
  for (int cl = 0; cl < CPG; ++cl) {
    int c = g * CPG + cl;
    float d = expf(la[(size_t)(c * CH + 63) * KD + kk]);
    size_t base = (size_t)cl * KD * VD;
#pragma unroll
    for (int i = 0; i < 16; ++i) {
      size_t idx = base + (size_t)(vv0 + r0 + 4 * i) * KD + kk;
      float u = (float)ustore[idx];
      s[i] = fmaf(d, s[i], u);
      ustore[idx] = tobf(s[i]);
    }
  }
  if (g < NGROUP - 1) {
#pragma unroll
    for (int i = 0; i < 16; ++i) {
      size_t o = (size_t)(vv0 + r0 + 4 * i) * KD + kk;
      Sinit[o] = s[i];
      ScarryB[o] = tobf(s[i]);
    }
  } else {
    // final state -> d_out (transpose [vv][kk] -> [kk][vv] via LDS)
#pragma unroll
    for (int i = 0; i < 16; ++i) tl[r0 + 4 * i][col] = s[i];
    __syncthreads();
#pragma unroll
    for (int i = 0; i < 16; ++i) {
      int kr = r0 + 4 * i;
      dstate[(size_t)(kk0 + kr) * VD + vv0 + col] = tl[col][kr];
    }
  }
}

// out_inter = q~_c @ S_{c-1}; accumulate into attn
__global__ __launch_bounds__(256) void k_inter(
    const bf16* __restrict__ qt, const bf16* __restrict__ ustore,
    const bf16* __restrict__ ScarryB, float* __restrict__ attn, int g)
{
  const int cl = blockIdx.y, c = g * CPG + cl;
  if (c == 0) return;  // S_{-1} = 0
  __shared__ __align__(16) bf16 sA[64 * 32];
  __shared__ __align__(16) bf16 sB[128 * 32];
  const bf16* B = (cl == 0) ? ScarryB : ustore + (size_t)(cl - 1) * KD * VD;
  const int n0 = blockIdx.x * 128;
  const int tid = threadIdx.x, lane = tid & 63;
  const int wr = (tid >> 6) >> 1, wc = (tid >> 6) & 1;
  f32x4 acc[8];
#pragma unroll
  for (int i = 0; i < 8; ++i) acc[i] = fzero();
  gemm_core<64, 128>(qt + (size_t)c * CH * KD, KD, 0, B, KD, n0, KD,
                     acc, sA, sB, tid);
#pragma unroll
  for (int m = 0; m < 2; ++m)
#pragma unroll
    for (int n = 0; n < 4; ++n) {
      f32x4 v = acc[m * 4 + n];
      int col = wc * 64 + n * 16 + (lane & 15);
#pragma unroll
      for (int r = 0; r < 4; ++r) {
        int row = wr * 32 + m * 16 + (lane >> 4) * 4 + r;
        attn[((size_t)c * CH + row) * VD + n0 + col] += v[r];
      }
    }
}

// y = attn_bf16 @ Wo^T + bo
__global__ __launch_bounds__(256) void k_out(
    const bf16* __restrict__ ob, const bf16* __restrict__ Wob,
    const float* __restrict__ bo, float* __restrict__ out)
{
  __shared__ __align__(16) bf16 sA[128 * 32];
  __shared__ __align__(16) bf16 sB[128 * 32];
  const int m0 = blockIdx.x * 128, n0 = blockIdx.y * 128;
  const int tid = threadIdx.x, lane = tid & 63;
  const int wr = (tid >> 6) >> 1, wc = (tid >> 6) & 1;
  f32x4 acc[16];
#pragma unroll
  for (int i = 0; i < 16; ++i) acc[i] = fzero();
  gemm_core<128, 128>(ob, VD, m0, Wob, VD, n0, VD, acc, sA, sB, tid);
#pragma unroll
  for (int m = 0; m < 4; ++m)
#pragma unroll
    for (int n = 0; n < 4; ++n) {
      f32x4 v = acc[m * 4 + n];
      int col = n0 + wc * 64 + n * 16 + (lane & 15);
      float b = bo[col];
#pragma unroll
      for (int r = 0; r < 4; ++r) {
        int row = m0 + wr * 64 + m * 16 + (lane >> 4) * 4 + r;
        out[(size_t)row * OD + col] = v[r] + b;
      }
    }
}

// ---------------------------------------------------------------------------
extern "C" void kernel_launch(void* const* d_in, const int* in_sizes, int n_in,
                              void* d_out, int out_size, void* d_ws, size_t ws_size,
                              hipStream_t stream)
{
  const float* hs = (const float*)d_in[0];
  const float* Wq = (const float*)d_in[1];
  const float* bq = (const float*)d_in[2];
  const float* Wk = (const float*)d_in[3];
  const float* bk = (const float*)d_in[4];
  const float* Wv = (const float*)d_in[5];
  const float* bv = (const float*)d_in[6];
  const float* Wg = (const float*)d_in[7];
  const float* bg = (const float*)d_in[8];
  const float* Wo = (const float*)d_in[9];
  const float* bo = (const float*)d_in[10];
  float* out = (float*)d_out;
  float* dstate = out + (size_t)T_ * OD;

  char* p = (char*)d_ws;
  auto alloc = [&](size_t b) -> char* {
    char* r = p; p += (b + 255) & ~(size_t)255; return r;
  };
  bf16* hsb    = (bf16*)alloc((size_t)T_ * H_ * 2);
  bf16* Wqb    = (bf16*)alloc((size_t)KD * H_ * 2);
  bf16* Wkb    = (bf16*)alloc((size_t)KD * H_ * 2);
  bf16* Wgb    = (bf16*)alloc((size_t)KD * H_ * 2);
  bf16* Wvb    = (bf16*)alloc((size_t)VD * H_ * 2);
  bf16* Wob    = (bf16*)alloc((size_t)OD * VD * 2);
  bf16* qb     = (bf16*)alloc((size_t)T_ * KD * 2);
  bf16* kb     = (bf16*)alloc((size_t)T_ * KD * 2);
  float* la    = (float*)alloc((size_t)T_ * KD * 4);
  bf16* vb     = (bf16*)alloc((size_t)T_ * VD * 2);
  bf16* qt     = (bf16*)alloc((size_t)T_ * KD * 2);
  bf16* kt     = (bf16*)alloc((size_t)T_ * KD * 2);
  bf16* kbarT  = (bf16*)alloc((size_t)T_ * KD * 2);
  bf16* vT     = (bf16*)alloc((size_t)T_ * VD * 2);
  float* attn  = (float*)alloc((size_t)T_ * VD * 4);
  bf16* ob     = (bf16*)alloc((size_t)T_ * VD * 2);
  float* Sinit = (float*)alloc((size_t)KD * VD * 4);
  bf16* ScarryB= (bf16*)alloc((size_t)KD * VD * 2);
  bf16* ustore = (bf16*)alloc((size_t)CPG * KD * VD * 2);
  if ((size_t)(p - (char*)d_ws) > ws_size) return;  // clean failure if ws too small

  // fp32 -> bf16 conversions
  k_cvt<<<T_ * H_ / 1024, 256, 0, stream>>>(hs, hsb, T_ * H_);
  k_cvt<<<KD * H_ / 1024, 256, 0, stream>>>(Wq, Wqb, KD * H_);
  k_cvt<<<KD * H_ / 1024, 256, 0, stream>>>(Wk, Wkb, KD * H_);
  k_cvt<<<KD * H_ / 1024, 256, 0, stream>>>(Wg, Wgb, KD * H_);
  k_cvt<<<VD * H_ / 1024, 256, 0, stream>>>(Wv, Wvb, VD * H_);
  k_cvt<<<OD * VD / 1024, 256, 0, stream>>>(Wo, Wob, OD * VD);

  // projections + activations
  k_proj<<<dim3(T_ / 128, 32), 256, 0, stream>>>(
      hsb, Wqb, Wkb, Wgb, Wvb, bq, bk, bg, bv, qb, kb, la, vb);

  // cumsum(log g) within chunks
  k_cumsum<<<(NCHUNK * KD) / 256, 256, 0, stream>>>(la);

  // decay-weighted operands + transposes
  k_transform<<<dim3(16, NCHUNK, 2), 256, 0, stream>>>(
      qb, kb, la, vb, qt, kt, kbarT, vT);

  // intra-chunk attention -> attn
  k_intra<<<NCHUNK, 256, 0, stream>>>(qt, kt, vT, attn);

  // chunk summaries, state scan, inter-chunk contribution (2 groups)
  for (int g = 0; g < NGROUP; ++g) {
    k_ugemm<<<dim3(8, 8, CPG), 256, 0, stream>>>(vT, kbarT, ustore, g);
    k_scan<<<dim3(16, 16), 256, 0, stream>>>(ustore, la, Sinit, ScarryB, dstate, g);
    k_inter<<<dim3(8, CPG), 256, 0, stream>>>(qt, ustore, ScarryB, attn, g);
  }

  // output projection
  k_cvt<<<T_ * VD / 1024, 256, 0, stream>>>(attn, ob, T_ * VD);
  k_out<<<dim3(T_ / 128, OD / 128), 256, 0, stream>>>(ob, Wob, bo, out);
}

// Round 2
// 650.870 us; speedup vs baseline: 1.0124x; 1.0124x over previous
//
#include <hip/hip_runtime.h>
#include <stdint.h>
#include <stddef.h>

// ---------------------------------------------------------------------------
// SimpleRNN (gated linear attention) — chunked parallel formulation.
//   q = hs@Wq^T+bq ; k = sig(hs@Wk^T+bk) ; g = sig(hs@Wg^T+bg) ; v = hs@Wv^T+bv
//   S_t = diag(g_t) S_{t-1} + k_t v_t^T ; out_t = q_t S_t ; y = out@Wo^T+bo
// Chunked (C=64): la = within-chunk inclusive cumsum(log g)
//   q~ = q*exp(la), k~ = k*exp(-la), kbar = k*exp(laC-la)
//   out = tril(q~ k~^T) V  +  q~ @ S_prev
//   U_c = kbar^T V ;  S_c = exp(laC) (.) S_{c-1} + U_c   (elementwise scan)
// GEMM core: 2-phase double-buffered LDS (T3-minimum), BK=32, gld_lds w=16.
// ---------------------------------------------------------------------------

#define DEVI __device__ __forceinline__

typedef __bf16 bf16;
typedef __bf16 bf16x8 __attribute__((ext_vector_type(8)));
typedef __bf16 bf16x4 __attribute__((ext_vector_type(4)));
typedef float  f32x4  __attribute__((ext_vector_type(4)));

static constexpr int T_  = 4096;
static constexpr int H_  = 2048;
static constexpr int KD  = 1024;
static constexpr int VD  = 1024;
static constexpr int OD  = 2048;
static constexpr int CH  = 64;                 // chunk length
static constexpr int NCHUNK = T_ / CH;         // 64
static constexpr int NGROUP = 2;               // chunk groups (ws economy)
static constexpr int CPG    = NCHUNK / NGROUP; // 32

DEVI bf16 tobf(float f) {
  union { float f; uint32_t u; } x; x.f = f;
  uint32_t r = (x.u + 0x7FFFu + ((x.u >> 16) & 1u)) >> 16;  // RNE
  union { uint16_t s; bf16 b; } y; y.s = (uint16_t)r;
  return y.b;
}

DEVI f32x4 fzero() { f32x4 z = {0.f, 0.f, 0.f, 0.f}; return z; }

// async global->LDS, 16B per lane (lane-linear LDS destination).
DEVI void gld16(const bf16* g, bf16* l) {
  auto* g1 = reinterpret_cast<__attribute__((address_space(1))) uint32_t*>(
      (uintptr_t)g);
  auto* l3 = reinterpret_cast<__attribute__((address_space(3))) uint32_t*>(
      (uintptr_t)l);
  __builtin_amdgcn_global_load_lds(g1, l3, 16, 0, 0);
}

// C[m0..+BM, n0..+BN] += A[M,K] * B[N,K]^T, both row-major K-contiguous.
// 4 waves in 2x2; per wave MR x NR 16x16 frags; BK=32; 2-phase LDS dbuf:
//   prologue stage(buf0); per iter: barrier(drains vmcnt) -> stage(next,
//   other buf) -> ds_read cur -> MFMA.  One barrier per K-step.
template<int BM, int BN>
DEVI void gemm_core(const bf16* A, int lda, int m0,
                    const bf16* B, int ldb, int n0,
                    int K, f32x4* acc, bf16* sA, bf16* sB, int tid)
{
  constexpr int MR = BM / 32;
  constexpr int NR = BN / 32;
  constexpr int ASZ = BM * 32;
  constexpr int BSZ = BN * 32;
  const int lane = tid & 63;
  const int wr = (tid >> 6) >> 1;
  const int wc = (tid >> 6) & 1;
  const int srow = tid >> 2;          // staging row within 64-row round
  const int skof = (tid & 3) * 8;     // staging k-offset (8 bf16 = 16B)

  auto stage = [&](int k0, int buf) {
#pragma unroll
    for (int r = 0; r < BM / 64; ++r)
      gld16(A + (size_t)(m0 + r * 64 + srow) * lda + k0 + skof,
            sA + buf * ASZ + r * 2048 + tid * 8);
#pragma unroll
    for (int r = 0; r < BN / 64; ++r)
      gld16(B + (size_t)(n0 + r * 64 + srow) * ldb + k0 + skof,
            sB + buf * BSZ + r * 2048 + tid * 8);
  };

  stage(0, 0);
  int cur = 0;
  const int nt = K / 32;
  for (int t = 0; t < nt; ++t) {
    __syncthreads();                 // compiler drains vmcnt(0)+lgkmcnt here
    if (t + 1 < nt) stage((t + 1) * 32, cur ^ 1);
    const bf16* pA = sA + cur * ASZ;
    const bf16* pB = sB + cur * BSZ;
    bf16x8 af[MR], bfr[NR];
#pragma unroll
    for (int m = 0; m < MR; ++m)
      af[m] = *(const bf16x8*)(pA + (wr * (MR * 16) + m * 16 + (lane & 15)) * 32
                               + (lane >> 4) * 8);
#pragma unroll
    for (int n = 0; n < NR; ++n)
      bfr[n] = *(const bf16x8*)(pB + (wc * (NR * 16) + n * 16 + (lane & 15)) * 32
                                + (lane >> 4) * 8);
#pragma unroll
    for (int m = 0; m < MR; ++m)
#pragma unroll
      for (int n = 0; n < NR; ++n)
        acc[m * NR + n] = __builtin_amdgcn_mfma_f32_16x16x32_bf16(
            af[m], bfr[n], acc[m * NR + n], 0, 0, 0);
    cur ^= 1;
  }
}

// ---------------------------------------------------------------------------
// one batched fp32->bf16 conversion for hs + the 5 weight matrices
static constexpr size_t CVT_HS = (size_t)T_ * H_;          // 8388608
static constexpr size_t CVT_W  = (size_t)KD * H_;          // 2097152 (Wq,Wk,Wg,Wv)
static constexpr size_t CVT_WO = (size_t)OD * VD;          // 2097152
static constexpr size_t CVT_TOT = CVT_HS + 4 * CVT_W + CVT_WO;

__global__ __launch_bounds__(256) void k_cvt6(
    const float* __restrict__ hs, const float* __restrict__ Wq,
    const float* __restrict__ Wk, const float* __restrict__ Wg,
    const float* __restrict__ Wv, const float* __restrict__ Wo,
    bf16* __restrict__ hsb, bf16* __restrict__ Wqb,
    bf16* __restrict__ Wkb, bf16* __restrict__ Wgb,
    bf16* __restrict__ Wvb, bf16* __restrict__ Wob)
{
  size_t i = ((size_t)blockIdx.x * 256 + threadIdx.x) * 4;
  if (i >= CVT_TOT) return;
  const float* s; bf16* d; size_t off;
  if (i < CVT_HS)                { s = hs; d = hsb; off = i; }
  else if (i < CVT_HS + CVT_W)   { s = Wq; d = Wqb; off = i - CVT_HS; }
  else if (i < CVT_HS + 2*CVT_W) { s = Wk; d = Wkb; off = i - CVT_HS - CVT_W; }
  else if (i < CVT_HS + 3*CVT_W) { s = Wg; d = Wgb; off = i - CVT_HS - 2*CVT_W; }
  else if (i < CVT_HS + 4*CVT_W) { s = Wv; d = Wvb; off = i - CVT_HS - 3*CVT_W; }
  else                           { s = Wo; d = Wob; off = i - CVT_HS - 4*CVT_W; }
  float4 v = *(const float4*)(s + off);
  bf16x4 o; o[0] = tobf(v.x); o[1] = tobf(v.y); o[2] = tobf(v.z); o[3] = tobf(v.w);
  *(bf16x4*)(d + off) = o;
}

__global__ __launch_bounds__(256) void k_cvt(const float* __restrict__ in,
                                             bf16* __restrict__ out, int n) {
  int i = (blockIdx.x * 256 + threadIdx.x) * 4;
  if (i >= n) return;
  float4 v = *(const float4*)(in + i);
  bf16x4 o; o[0] = tobf(v.x); o[1] = tobf(v.y); o[2] = tobf(v.z); o[3] = tobf(v.w);
  *(bf16x4*)(out + i) = o;
}

// Projections: N = [q(1024) | k | g | v]; per-segment epilogue.
__global__ __launch_bounds__(256) void k_proj(
    const bf16* __restrict__ hsb,
    const bf16* __restrict__ Wqb, const bf16* __restrict__ Wkb,
    const bf16* __restrict__ Wgb, const bf16* __restrict__ Wvb,
    const float* __restrict__ bq, const float* __restrict__ bk,
    const float* __restrict__ bg, const float* __restrict__ bv,
    bf16* __restrict__ qb, bf16* __restrict__ kb,
    float* __restrict__ la, bf16* __restrict__ vb)
{
  __shared__ __align__(16) bf16 sA[2 * 128 * 32];
  __shared__ __align__(16) bf16 sB[2 * 128 * 32];
  const int m0 = blockIdx.x * 128;
  const int nseg = blockIdx.y;          // 0..31
  const int seg = nseg >> 3;            // 0..3
  const int n0 = (nseg & 7) * 128;      // within segment
  const bf16* W = seg == 0 ? Wqb : seg == 1 ? Wkb : seg == 2 ? Wgb : Wvb;
  const float* bias = seg == 0 ? bq : seg == 1 ? bk : seg == 2 ? bg : bv;
  const int tid = threadIdx.x, lane = tid & 63;
  const int wr = (tid >> 6) >> 1, wc = (tid >> 6) & 1;
  f32x4 acc[16];
#pragma unroll
  for (int i = 0; i < 16; ++i) acc[i] = fzero();
  gemm_core<128, 128>(hsb, H_, m0, W, H_, n0, H_, acc, sA, sB, tid);
#pragma unroll
  for (int m = 0; m < 4; ++m)
#pragma unroll
    for (int n = 0; n < 4; ++n) {
      f32x4 v = acc[m * 4 + n];
      int col = n0 + wc * 64 + n * 16 + (lane & 15);
      float b = bias[col];
#pragma unroll
      for (int r = 0; r < 4; ++r) {
        int row = m0 + wr * 64 + m * 16 + (lane >> 4) * 4 + r;
        float x = v[r] + b;
        size_t o = (size_t)row * KD + col;
        if (seg == 0)      qb[o] = tobf(x);
        else if (seg == 1) kb[o] = tobf(1.f / (1.f + expf(-x)));
        else if (seg == 2) la[o] = fminf(x, 0.f) - log1pf(expf(-fabsf(x)));
        else               vb[o] = tobf(x);
      }
    }
}

// within-chunk inclusive cumsum of log g (in place)
__global__ __launch_bounds__(256) void k_cumsum(float* __restrict__ la) {
  int gid = blockIdx.x * 256 + threadIdx.x;
  int c = gid >> 10, kk = gid & 1023;
  size_t base = (size_t)c * CH * KD + kk;
  float s = 0.f;
  for (int i = 0; i < CH; ++i) {
    s += la[base + (size_t)i * KD];
    la[base + (size_t)i * KD] = s;
  }
}

// q~,k~ (t-major) ; kbar^T [c][kk][t] ; V^T [c][vv][t]
__global__ __launch_bounds__(256) void k_transform(
    const bf16* __restrict__ qb, const bf16* __restrict__ kb,
    const float* __restrict__ la, const bf16* __restrict__ vb,
    bf16* __restrict__ qt, bf16* __restrict__ kt,
    bf16* __restrict__ kbarT, bf16* __restrict__ vT)
{
  __shared__ bf16 tr[64][72];
  const int c = blockIdx.y, tile = blockIdx.x, path = blockIdx.z;
  const int tid = threadIdx.x;
  const int colL = tid & 63;
  const int rbase = tid >> 6;
  if (path == 0) {
    const int kk0 = tile * 64;
    const int kk = kk0 + colL;
    const float lc = la[(size_t)(c * CH + 63) * KD + kk];
#pragma unroll
    for (int i = 0; i < 16; ++i) {
      int tl = rbase + 4 * i;
      size_t idx = (size_t)(c * CH + tl) * KD + kk;
      float lav = la[idx];
      float qv = (float)qb[idx];
      float kv = (float)kb[idx];
      qt[idx] = tobf(qv * expf(lav));
      kt[idx] = tobf(kv * expf(-lav));
      tr[colL][tl] = tobf(kv * expf(lc - lav));   // kbar, staged for transpose
    }
    __syncthreads();
#pragma unroll
    for (int i = 0; i < 16; ++i) {
      int row = rbase + 4 * i;
      kbarT[((size_t)c * KD + kk0 + row) * 64 + colL] = tr[row][colL];
    }
  } else {
    const int vv0 = tile * 64;
#pragma unroll
    for (int i = 0; i < 16; ++i) {
      int tl = rbase + 4 * i;
      tr[colL][tl] = vb[(size_t)(c * CH + tl) * VD + vv0 + colL];
    }
    __syncthreads();
#pragma unroll
    for (int i = 0; i < 16; ++i) {
      int row = rbase + 4 * i;
      vT[((size_t)c * VD + vv0 + row) * 64 + colL] = tr[row][colL];
    }
  }
}

// intra-chunk: P = tril(q~ k~^T) (64x64), out_intra = P @ V -> attn (fp32)
__global__ __launch_bounds__(256) void k_intra(
    const bf16* __restrict__ qt, const bf16* __restrict__ kt,
    const bf16* __restrict__ vT, float* __restrict__ attn)
{
  __shared__ __align__(16) bf16 sA[2 * 64 * 32];
  __shared__ __align__(16) bf16 sB[2 * 64 * 32];
  __shared__ __align__(16) bf16 sV[128 * 72];   // padded V^T slice
  __shared__ __align__(16) bf16 Pl[64 * 72];    // padded P
  const int c = blockIdx.x;
  const int tid = threadIdx.x, lane = tid & 63;
  const int wr = (tid >> 6) >> 1, wc = (tid >> 6) & 1;
  f32x4 acc[4];
#pragma unroll
  for (int i = 0; i < 4; ++i) acc[i] = fzero();
  gemm_core<64, 64>(qt + (size_t)c * CH * KD, KD, 0,
                    kt + (size_t)c * CH * KD, KD, 0, KD, acc, sA, sB, tid);
  // mask (j<=t) and store P as bf16
#pragma unroll
  for (int m = 0; m < 2; ++m)
#pragma unroll
    for (int n = 0; n < 2; ++n) {
      f32x4 v = acc[m * 2 + n];
      int j = wc * 32 + n * 16 + (lane & 15);
#pragma unroll
      for (int r = 0; r < 4; ++r) {
        int t = wr * 32 + m * 16 + (lane >> 4) * 4 + r;
        Pl[t * 72 + j] = (j <= t) ? tobf(v[r]) : tobf(0.f);
      }
    }
  for (int nb = 0; nb < 8; ++nb) {
    __syncthreads();
    // stage V^T rows [nb*128, nb*128+128), padded stride 72
#pragma unroll
    for (int rr = 0; rr < 4; ++rr) {
      int row = rr * 32 + (tid >> 3);
      int j0 = (tid & 7) * 8;
      bf16x8 vv = *(const bf16x8*)(vT + ((size_t)c * VD + nb * 128 + row) * 64 + j0);
      *(bf16x8*)(sV + row * 72 + j0) = vv;
    }
    __syncthreads();
    f32x4 a2[8];
#pragma unroll
    for (int i = 0; i < 8; ++i) a2[i] = fzero();
#pragma unroll
    for (int ks = 0; ks < 64; ks += 32) {
      bf16x8 af[2], bfr[4];
#pragma unroll
      for (int m = 0; m < 2; ++m)
        af[m] = *(const bf16x8*)(Pl + (wr * 32 + m * 16 + (lane & 15)) * 72
                                 + ks + (lane >> 4) * 8);
#pragma unroll
      for (int n = 0; n < 4; ++n)
        bfr[n] = *(const bf16x8*)(sV + (wc * 64 + n * 16 + (lane & 15)) * 72
                                  + ks + (lane >> 4) * 8);
#pragma unroll
      for (int m = 0; m < 2; ++m)
#pragma unroll
        for (int n = 0; n < 4; ++n)
          a2[m * 4 + n] = __builtin_amdgcn_mfma_f32_16x16x32_bf16(
              af[m], bfr[n], a2[m * 4 + n], 0, 0, 0);
    }
#pragma unroll
    for (int m = 0; m < 2; ++m)
#pragma unroll
      for (int n = 0; n < 4; ++n) {
        int col = wc * 64 + n * 16 + (lane & 15);
#pragma unroll
        for (int r = 0; r < 4; ++r) {
          int row = wr * 32 + m * 16 + (lane >> 4) * 4 + r;
          attn[((size_t)c * CH + row) * VD + nb * 128 + col] = a2[m * 4 + n][r];
        }
      }
  }
}

// U^T[vv][kk] = sum_j V[j,vv] kbar[j,kk]  -> ustore slot (bf16)
__global__ __launch_bounds__(256) void k_ugemm(
    const bf16* __restrict__ vT, const bf16* __restrict__ kbarT,
    bf16* __restrict__ ustore, int g)
{
  __shared__ __align__(16) bf16 sA[2 * 128 * 32];
  __shared__ __align__(16) bf16 sB[2 * 128 * 32];
  const int cl = blockIdx.z, c = g * CPG + cl;
  const int m0 = blockIdx.x * 128, n0 = blockIdx.y * 128;
  const int tid = threadIdx.x, lane = tid & 63;
  const int wr = (tid >> 6) >> 1, wc = (tid >> 6) & 1;
  f32x4 acc[16];
#pragma unroll
  for (int i = 0; i < 16; ++i) acc[i] = fzero();
  gemm_core<128, 128>(vT + (size_t)c * VD * 64, 64, m0,
                      kbarT + (size_t)c * KD * 64, 64, n0, 64, acc, sA, sB, tid);
  bf16* dst = ustore + (size_t)cl * KD * VD;
#pragma unroll
  for (int m = 0; m < 4; ++m)
#pragma unroll
    for (int n = 0; n < 4; ++n) {
      f32x4 v = acc[m * 4 + n];
      int col = wc * 64 + n * 16 + (lane & 15);
#pragma unroll
      for (int r = 0; r < 4; ++r) {
        int row = wr * 64 + m * 16 + (lane >> 4) * 4 + r;
        dst[(size_t)(m0 + row) * KD + n0 + col] = tobf(v[r]);
      }
    }
}

// elementwise scan over chunks (in place: slot c becomes state AFTER chunk c)
__global__ __launch_bounds__(256) void k_scan(
    bf16* __restrict__ ustore, const float* __restrict__ la,
    float* __restrict__ Sinit, bf16* __restrict__ ScarryB,
    float* __restrict__ dstate, int g)
{
  __shared__ float tl[64][65];
  const int vv0 = blockIdx.x * 64, kk0 = blockIdx.y * 64;
  const int tid = threadIdx.x;
  const int col = tid & 63;       // kk local
  const int r0 = tid >> 6;        // 0..3 (vv local base)
  const int kk = kk0 + col;
  float s[16];
  if (g == 0) {
#pragma unroll
    for (int i = 0; i < 16; ++i) s[i] = 0.f;
  } else {
#pragma unroll
    for (int i = 0; i < 16; ++i)
      s[i] = Sinit[(size_t)(vv0 + r0 + 4 * i) * KD + kk];
  }
  for (int cl = 0; cl < CPG; ++cl) {
    int c = g * CPG + cl;
    float d = expf(la[(size_t)(c * CH + 63) * KD + kk]);
    size_t base = (size_t)cl * KD * VD;
#pragma unroll
    for (int i = 0; i < 16; ++i) {
      size_t idx = base + (size_t)(vv0 + r0 + 4 * i) * KD + kk;
      float u = (float)ustore[idx];
      s[i] = fmaf(d, s[i], u);
      ustore[idx] = tobf(s[i]);
    }
  }
  if (g < NGROUP - 1) {
#pragma unroll
    for (int i = 0; i < 16; ++i) {
      size_t o = (size_t)(vv0 + r0 + 4 * i) * KD + kk;
      Sinit[o] = s[i];
      ScarryB[o] = tobf(s[i]);
    }
  } else {
    // final state -> d_out (transpose [vv][kk] -> [kk][vv] via LDS)
#pragma unroll
    for (int i = 0; i < 16; ++i) tl[r0 + 4 * i][col] = s[i];
    __syncthreads();
#pragma unroll
    for (int i = 0; i < 16; ++i) {
      int kr = r0 + 4 * i;
      dstate[(size_t)(kk0 + kr) * VD + vv0 + col] = tl[col][kr];
    }
  }
}

// out_inter = q~_c @ S_{c-1}; accumulate into attn
__global__ __launch_bounds__(256) void k_inter(
    const bf16* __restrict__ qt, const bf16* __restrict__ ustore,
    const bf16* __restrict__ ScarryB, float* __restrict__ attn, int g)
{
  const int cl = blockIdx.y, c = g * CPG + cl;
  if (c == 0) return;  // S_{-1} = 0
  __shared__ __align__(16) bf16 sA[2 * 64 * 32];
  __shared__ __align__(16) bf16 sB[2 * 128 * 32];
  const bf16* B = (cl == 0) ? ScarryB : ustore + (size_t)(cl - 1) * KD * VD;
  const int n0 = blockIdx.x * 128;
  const int tid = threadIdx.x, lane = tid & 63;
  const int wr = (tid >> 6) >> 1, wc = (tid >> 6) & 1;
  f32x4 acc[8];
#pragma unroll
  for (int i = 0; i < 8; ++i) acc[i] = fzero();
  gemm_core<64, 128>(qt + (size_t)c * CH * KD, KD, 0, B, KD, n0, KD,
                     acc, sA, sB, tid);
#pragma unroll
  for (int m = 0; m < 2; ++m)
#pragma unroll
    for (int n = 0; n < 4; ++n) {
      f32x4 v = acc[m * 4 + n];
      int col = wc * 64 + n * 16 + (lane & 15);
#pragma unroll
      for (int r = 0; r < 4; ++r) {
        int row = wr * 32 + m * 16 + (lane >> 4) * 4 + r;
        attn[((size_t)c * CH + row) * VD + n0 + col] += v[r];
      }
    }
}

// y = attn_bf16 @ Wo^T + bo
__global__ __launch_bounds__(256) void k_out(
    const bf16* __restrict__ ob, const bf16* __restrict__ Wob,
    const float* __restrict__ bo, float* __restrict__ out)
{
  __shared__ __align__(16) bf16 sA[2 * 128 * 32];
  __shared__ __align__(16) bf16 sB[2 * 128 * 32];
  const int m0 = blockIdx.x * 128, n0 = blockIdx.y * 128;
  const int tid = threadIdx.x, lane = tid & 63;
  const int wr = (tid >> 6) >> 1, wc = (tid >> 6) & 1;
  f32x4 acc[16];
#pragma unroll
  for (int i = 0; i < 16; ++i) acc[i] = fzero();
  gemm_core<128, 128>(ob, VD, m0, Wob, VD, n0, VD, acc, sA, sB, tid);
#pragma unroll
  for (int m = 0; m < 4; ++m)
#pragma unroll
    for (int n = 0; n < 4; ++n) {
      f32x4 v = acc[m * 4 + n];
      int col = n0 + wc * 64 + n * 16 + (lane & 15);
      float b = bo[col];
#pragma unroll
      for (int r = 0; r < 4; ++r) {
        int row = m0 + wr * 64 + m * 16 + (lane >> 4) * 4 + r;
        out[(size_t)row * OD + col] = v[r] + b;
      }
    }
}

// ---------------------------------------------------------------------------
extern "C" void kernel_launch(void* const* d_in, const int* in_sizes, int n_in,
                              void* d_out, int out_size, void* d_ws, size_t ws_size,
                              hipStream_t stream)
{
  const float* hs = (const float*)d_in[0];
  const float* Wq = (const float*)d_in[1];
  const float* bq = (const float*)d_in[2];
  const float* Wk = (const float*)d_in[3];
  const float* bk = (const float*)d_in[4];
  const float* Wv = (const float*)d_in[5];
  const float* bv = (const float*)d_in[6];
  const float* Wg = (const float*)d_in[7];
  const float* bg = (const float*)d_in[8];
  const float* Wo = (const float*)d_in[9];
  const float* bo = (const float*)d_in[10];
  float* out = (float*)d_out;
  float* dstate = out + (size_t)T_ * OD;

  char* p = (char*)d_ws;
  auto alloc = [&](size_t b) -> char* {
    char* r = p; p += (b + 255) & ~(size_t)255; return r;
  };
  bf16* hsb    = (bf16*)alloc((size_t)T_ * H_ * 2);
  bf16* Wqb    = (bf16*)alloc((size_t)KD * H_ * 2);
  bf16* Wkb    = (bf16*)alloc((size_t)KD * H_ * 2);
  bf16* Wgb    = (bf16*)alloc((size_t)KD * H_ * 2);
  bf16* Wvb    = (bf16*)alloc((size_t)VD * H_ * 2);
  bf16* Wob    = (bf16*)alloc((size_t)OD * VD * 2);
  bf16* qb     = (bf16*)alloc((size_t)T_ * KD * 2);
  bf16* kb     = (bf16*)alloc((size_t)T_ * KD * 2);
  float* la    = (float*)alloc((size_t)T_ * KD * 4);
  bf16* vb     = (bf16*)alloc((size_t)T_ * VD * 2);
  bf16* qt     = (bf16*)alloc((size_t)T_ * KD * 2);
  bf16* kt     = (bf16*)alloc((size_t)T_ * KD * 2);
  bf16* kbarT  = (bf16*)alloc((size_t)T_ * KD * 2);
  bf16* vT     = (bf16*)alloc((size_t)T_ * VD * 2);
  float* attn  = (float*)alloc((size_t)T_ * VD * 4);
  bf16* ob     = (bf16*)alloc((size_t)T_ * VD * 2);
  float* Sinit = (float*)alloc((size_t)KD * VD * 4);
  bf16* ScarryB= (bf16*)alloc((size_t)KD * VD * 2);
  bf16* ustore = (bf16*)alloc((size_t)CPG * KD * VD * 2);
  if ((size_t)(p - (char*)d_ws) > ws_size) return;  // clean failure if ws too small

  // fp32 -> bf16 conversions (batched)
  k_cvt6<<<(int)((CVT_TOT / 4 + 255) / 256), 256, 0, stream>>>(
      hs, Wq, Wk, Wg, Wv, Wo, hsb, Wqb, Wkb, Wgb, Wvb, Wob);

  // projections + activations
  k_proj<<<dim3(T_ / 128, 32), 256, 0, stream>>>(
      hsb, Wqb, Wkb, Wgb, Wvb, bq, bk, bg, bv, qb, kb, la, vb);

  // cumsum(log g) within chunks
  k_cumsum<<<(NCHUNK * KD) / 256, 256, 0, stream>>>(la);

  // decay-weighted operands + transposes
  k_transform<<<dim3(16, NCHUNK, 2), 256, 0, stream>>>(
      qb, kb, la, vb, qt, kt, kbarT, vT);

  // intra-chunk attention -> attn
  k_intra<<<NCHUNK, 256, 0, stream>>>(qt, kt, vT, attn);

  // chunk summaries, state scan, inter-chunk contribution (2 groups)
  for (int g = 0; g < NGROUP; ++g) {
    k_ugemm<<<dim3(8, 8, CPG), 256, 0, stream>>>(vT, kbarT, ustore, g);
    k_scan<<<dim3(16, 16), 256, 0, stream>>>(ustore, la, Sinit, ScarryB, dstate, g);
    k_inter<<<dim3(8, CPG), 256, 0, stream>>>(qt, ustore, ScarryB, attn, g);
  }

  // output projection
  k_cvt<<<T_ * VD / 1024, 256, 0, stream>>>(attn, ob, T_ * VD);
  k_out<<<dim3(T_ / 128, OD / 128), 256, 0, stream>>>(ob, Wob, bo, out);
}

// Round 3
// 638.286 us; speedup vs baseline: 1.0323x; 1.0197x over previous
//
#include <hip/hip_runtime.h>
#include <stdint.h>
#include <stddef.h>

// ---------------------------------------------------------------------------
// SimpleRNN (gated linear attention) — chunked parallel formulation.
//   q = hs@Wq^T+bq ; k = sig(hs@Wk^T+bk) ; g = sig(hs@Wg^T+bg) ; v = hs@Wv^T+bv
//   S_t = diag(g_t) S_{t-1} + k_t v_t^T ; out_t = q_t S_t ; y = out@Wo^T+bo
// Chunked (C=64): la = within-chunk inclusive cumsum(log g)
//   q~ = q*exp(la), k~ = k*exp(-la), kbar = k*exp(laC-la)
//   out = tril(q~ k~^T) V  +  q~ @ S_prev
//   U_c = kbar^T V ;  S_c = exp(laC) (.) S_{c-1} + U_c   (elementwise scan)
// GEMM core: 3-buffer depth-2 pipeline, counted s_waitcnt vmcnt(N) (T3+T4),
// raw s_barrier, BK=32, global_load_lds width=16.
// ---------------------------------------------------------------------------

#define DEVI __device__ __forceinline__

typedef __bf16 bf16;
typedef __bf16 bf16x8 __attribute__((ext_vector_type(8)));
typedef __bf16 bf16x4 __attribute__((ext_vector_type(4)));
typedef float  f32x4  __attribute__((ext_vector_type(4)));

static constexpr int T_  = 4096;
static constexpr int H_  = 2048;
static constexpr int KD  = 1024;
static constexpr int VD  = 1024;
static constexpr int OD  = 2048;
static constexpr int CH  = 64;                 // chunk length
static constexpr int NCHUNK = T_ / CH;         // 64
static constexpr int NGROUP = 2;               // chunk groups (ws economy)
static constexpr int CPG    = NCHUNK / NGROUP; // 32

DEVI bf16 tobf(float f) {
  union { float f; uint32_t u; } x; x.f = f;
  uint32_t r = (x.u + 0x7FFFu + ((x.u >> 16) & 1u)) >> 16;  // RNE
  union { uint16_t s; bf16 b; } y; y.s = (uint16_t)r;
  return y.b;
}

DEVI f32x4 fzero() { f32x4 z = {0.f, 0.f, 0.f, 0.f}; return z; }

// async global->LDS, 16B per lane (lane-linear LDS destination).
DEVI void gld16(const bf16* g, bf16* l) {
  auto* g1 = reinterpret_cast<__attribute__((address_space(1))) uint32_t*>(
      (uintptr_t)g);
  auto* l3 = reinterpret_cast<__attribute__((address_space(3))) uint32_t*>(
      (uintptr_t)l);
  __builtin_amdgcn_global_load_lds(g1, l3, 16, 0, 0);
}

template<int N> DEVI void waitvm() {
  if constexpr (N == 0) asm volatile("s_waitcnt vmcnt(0)" ::: "memory");
  else if constexpr (N == 2) asm volatile("s_waitcnt vmcnt(2)" ::: "memory");
  else if constexpr (N == 3) asm volatile("s_waitcnt vmcnt(3)" ::: "memory");
  else if constexpr (N == 4) asm volatile("s_waitcnt vmcnt(4)" ::: "memory");
  else static_assert(N == 0, "unsupported vmcnt");
}

// C[m0..+BM, n0..+BN] += A[M,K] * B[N,K]^T, both row-major K-contiguous.
// 4 waves in 2x2; per wave MR x NR 16x16 frags; BK=32.
// 3-buffer depth-2 counted pipeline:
//   prologue: stage(0,b0); stage(1,b1)
//   iter t  : waitcnt vmcnt(LOADS)   // own tile-t loads retired, t+1 in flight
//             s_barrier              // tile t published by ALL waves
//             stage(t+2, (t+2)%3)    // overwrites (t-1)%3: reads done pre-bar
//             ds_read buf t%3 -> MFMA
// Never drains vmcnt to 0 except the final iteration.
template<int BM, int BN>
DEVI void gemm_core(const bf16* A, int lda, int m0,
                    const bf16* B, int ldb, int n0,
                    int K, f32x4* acc, bf16* sA, bf16* sB, int tid)
{
  constexpr int MR = BM / 32;
  constexpr int NR = BN / 32;
  constexpr int ASZ = BM * 32;
  constexpr int BSZ = BN * 32;
  constexpr int LOADS = BM / 64 + BN / 64;   // VMEM instrs per stage per wave
  const int lane = tid & 63;
  const int wr = (tid >> 6) >> 1;
  const int wc = (tid >> 6) & 1;
  const int srow = tid >> 2;          // staging row within 64-row round
  const int skof = (tid & 3) * 8;     // staging k-offset (8 bf16 = 16B)
  const bf16* aB = A + (size_t)(m0 + srow) * lda + skof;
  const bf16* bB = B + (size_t)(n0 + srow) * ldb + skof;

  auto stage = [&](int t, int buf) {
    const int k0 = t * 32;
#pragma unroll
    for (int r = 0; r < BM / 64; ++r)
      gld16(aB + (size_t)r * 64 * lda + k0, sA + buf * ASZ + r * 2048 + tid * 8);
#pragma unroll
    for (int r = 0; r < BN / 64; ++r)
      gld16(bB + (size_t)r * 64 * ldb + k0, sB + buf * BSZ + r * 2048 + tid * 8);
  };

  const int nt = K / 32;
  stage(0, 0);
  if (nt > 1) stage(1, 1);
  int cur = 0;
  for (int t = 0; t < nt; ++t) {
    if (t < nt - 1) waitvm<LOADS>();
    else            waitvm<0>();
    __builtin_amdgcn_s_barrier();
    __builtin_amdgcn_sched_barrier(0);
    if (t + 2 < nt) {
      int b2 = cur + 2; if (b2 >= 3) b2 -= 3;
      stage(t + 2, b2);
    }
    const bf16* pA = sA + cur * ASZ;
    const bf16* pB = sB + cur * BSZ;
    bf16x8 af[MR], bfr[NR];
#pragma unroll
    for (int m = 0; m < MR; ++m)
      af[m] = *(const bf16x8*)(pA + (wr * (MR * 16) + m * 16 + (lane & 15)) * 32
                               + (lane >> 4) * 8);
#pragma unroll
    for (int n = 0; n < NR; ++n)
      bfr[n] = *(const bf16x8*)(pB + (wc * (NR * 16) + n * 16 + (lane & 15)) * 32
                                + (lane >> 4) * 8);
#pragma unroll
    for (int m = 0; m < MR; ++m)
#pragma unroll
      for (int n = 0; n < NR; ++n)
        acc[m * NR + n] = __builtin_amdgcn_mfma_f32_16x16x32_bf16(
            af[m], bfr[n], acc[m * NR + n], 0, 0, 0);
    ++cur; if (cur >= 3) cur -= 3;
  }
}

// ---------------------------------------------------------------------------
// one batched fp32->bf16 conversion for hs + the 5 weight matrices
static constexpr size_t CVT_HS = (size_t)T_ * H_;          // 8388608
static constexpr size_t CVT_W  = (size_t)KD * H_;          // 2097152 (Wq,Wk,Wg,Wv)
static constexpr size_t CVT_WO = (size_t)OD * VD;          // 2097152
static constexpr size_t CVT_TOT = CVT_HS + 4 * CVT_W + CVT_WO;

__global__ __launch_bounds__(256) void k_cvt6(
    const float* __restrict__ hs, const float* __restrict__ Wq,
    const float* __restrict__ Wk, const float* __restrict__ Wg,
    const float* __restrict__ Wv, const float* __restrict__ Wo,
    bf16* __restrict__ hsb, bf16* __restrict__ Wqb,
    bf16* __restrict__ Wkb, bf16* __restrict__ Wgb,
    bf16* __restrict__ Wvb, bf16* __restrict__ Wob)
{
  size_t i = ((size_t)blockIdx.x * 256 + threadIdx.x) * 4;
  if (i >= CVT_TOT) return;
  const float* s; bf16* d; size_t off;
  if (i < CVT_HS)                { s = hs; d = hsb; off = i; }
  else if (i < CVT_HS + CVT_W)   { s = Wq; d = Wqb; off = i - CVT_HS; }
  else if (i < CVT_HS + 2*CVT_W) { s = Wk; d = Wkb; off = i - CVT_HS - CVT_W; }
  else if (i < CVT_HS + 3*CVT_W) { s = Wg; d = Wgb; off = i - CVT_HS - 2*CVT_W; }
  else if (i < CVT_HS + 4*CVT_W) { s = Wv; d = Wvb; off = i - CVT_HS - 3*CVT_W; }
  else                           { s = Wo; d = Wob; off = i - CVT_HS - 4*CVT_W; }
  float4 v = *(const float4*)(s + off);
  bf16x4 o; o[0] = tobf(v.x); o[1] = tobf(v.y); o[2] = tobf(v.z); o[3] = tobf(v.w);
  *(bf16x4*)(d + off) = o;
}

__global__ __launch_bounds__(256) void k_cvt(const float* __restrict__ in,
                                             bf16* __restrict__ out, int n) {
  int i = (blockIdx.x * 256 + threadIdx.x) * 4;
  if (i >= n) return;
  float4 v = *(const float4*)(in + i);
  bf16x4 o; o[0] = tobf(v.x); o[1] = tobf(v.y); o[2] = tobf(v.z); o[3] = tobf(v.w);
  *(bf16x4*)(out + i) = o;
}

// Projections: N = [q(1024) | k | g | v]; per-segment epilogue.
__global__ __launch_bounds__(256) void k_proj(
    const bf16* __restrict__ hsb,
    const bf16* __restrict__ Wqb, const bf16* __restrict__ Wkb,
    const bf16* __restrict__ Wgb, const bf16* __restrict__ Wvb,
    const float* __restrict__ bq, const float* __restrict__ bk,
    const float* __restrict__ bg, const float* __restrict__ bv,
    bf16* __restrict__ qb, bf16* __restrict__ kb,
    float* __restrict__ la, bf16* __restrict__ vb)
{
  __shared__ __align__(16) bf16 sA[3 * 128 * 32];
  __shared__ __align__(16) bf16 sB[3 * 128 * 32];
  const int m0 = blockIdx.x * 128;
  const int nseg = blockIdx.y;          // 0..31
  const int seg = nseg >> 3;            // 0..3
  const int n0 = (nseg & 7) * 128;      // within segment
  const bf16* W = seg == 0 ? Wqb : seg == 1 ? Wkb : seg == 2 ? Wgb : Wvb;
  const float* bias = seg == 0 ? bq : seg == 1 ? bk : seg == 2 ? bg : bv;
  const int tid = threadIdx.x, lane = tid & 63;
  const int wr = (tid >> 6) >> 1, wc = (tid >> 6) & 1;
  f32x4 acc[16];
#pragma unroll
  for (int i = 0; i < 16; ++i) acc[i] = fzero();
  gemm_core<128, 128>(hsb, H_, m0, W, H_, n0, H_, acc, sA, sB, tid);
#pragma unroll
  for (int m = 0; m < 4; ++m)
#pragma unroll
    for (int n = 0; n < 4; ++n) {
      f32x4 v = acc[m * 4 + n];
      int col = n0 + wc * 64 + n * 16 + (lane & 15);
      float b = bias[col];
#pragma unroll
      for (int r = 0; r < 4; ++r) {
        int row = m0 + wr * 64 + m * 16 + (lane >> 4) * 4 + r;
        float x = v[r] + b;
        size_t o = (size_t)row * KD + col;
        if (seg == 0)      qb[o] = tobf(x);
        else if (seg == 1) kb[o] = tobf(1.f / (1.f + expf(-x)));
        else if (seg == 2) la[o] = fminf(x, 0.f) - log1pf(expf(-fabsf(x)));
        else               vb[o] = tobf(x);
      }
    }
}

// within-chunk inclusive cumsum of log g (in place)
__global__ __launch_bounds__(256) void k_cumsum(float* __restrict__ la) {
  int gid = blockIdx.x * 256 + threadIdx.x;
  int c = gid >> 10, kk = gid & 1023;
  size_t base = (size_t)c * CH * KD + kk;
  float s = 0.f;
  for (int i = 0; i < CH; ++i) {
    s += la[base + (size_t)i * KD];
    la[base + (size_t)i * KD] = s;
  }
}

// q~,k~ (t-major) ; kbar^T [c][kk][t] ; V^T [c][vv][t]
__global__ __launch_bounds__(256) void k_transform(
    const bf16* __restrict__ qb, const bf16* __restrict__ kb,
    const float* __restrict__ la, const bf16* __restrict__ vb,
    bf16* __restrict__ qt, bf16* __restrict__ kt,
    bf16* __restrict__ kbarT, bf16* __restrict__ vT)
{
  __shared__ bf16 tr[64][72];
  const int c = blockIdx.y, tile = blockIdx.x, path = blockIdx.z;
  const int tid = threadIdx.x;
  const int colL = tid & 63;
  const int rbase = tid >> 6;
  if (path == 0) {
    const int kk0 = tile * 64;
    const int kk = kk0 + colL;
    const float lc = la[(size_t)(c * CH + 63) * KD + kk];
#pragma unroll
    for (int i = 0; i < 16; ++i) {
      int tl = rbase + 4 * i;
      size_t idx = (size_t)(c * CH + tl) * KD + kk;
      float lav = la[idx];
      float qv = (float)qb[idx];
      float kv = (float)kb[idx];
      qt[idx] = tobf(qv * expf(lav));
      kt[idx] = tobf(kv * expf(-lav));
      tr[colL][tl] = tobf(kv * expf(lc - lav));   // kbar, staged for transpose
    }
    __syncthreads();
#pragma unroll
    for (int i = 0; i < 16; ++i) {
      int row = rbase + 4 * i;
      kbarT[((size_t)c * KD + kk0 + row) * 64 + colL] = tr[row][colL];
    }
  } else {
    const int vv0 = tile * 64;
#pragma unroll
    for (int i = 0; i < 16; ++i) {
      int tl = rbase + 4 * i;
      tr[colL][tl] = vb[(size_t)(c * CH + tl) * VD + vv0 + colL];
    }
    __syncthreads();
#pragma unroll
    for (int i = 0; i < 16; ++i) {
      int row = rbase + 4 * i;
      vT[((size_t)c * VD + vv0 + row) * 64 + colL] = tr[row][colL];
    }
  }
}

// intra-chunk: P = tril(q~ k~^T) (64x64), out_intra = P @ V -> attn (fp32)
__global__ __launch_bounds__(256) void k_intra(
    const bf16* __restrict__ qt, const bf16* __restrict__ kt,
    const bf16* __restrict__ vT, float* __restrict__ attn)
{
  __shared__ __align__(16) bf16 sA[3 * 64 * 32];
  __shared__ __align__(16) bf16 sB[3 * 64 * 32];
  __shared__ __align__(16) bf16 sV[128 * 72];   // padded V^T slice
  __shared__ __align__(16) bf16 Pl[64 * 72];    // padded P
  const int c = blockIdx.x;
  const int tid = threadIdx.x, lane = tid & 63;
  const int wr = (tid >> 6) >> 1, wc = (tid >> 6) & 1;
  f32x4 acc[4];
#pragma unroll
  for (int i = 0; i < 4; ++i) acc[i] = fzero();
  gemm_core<64, 64>(qt + (size_t)c * CH * KD, KD, 0,
                    kt + (size_t)c * CH * KD, KD, 0, KD, acc, sA, sB, tid);
  // mask (j<=t) and store P as bf16
#pragma unroll
  for (int m = 0; m < 2; ++m)
#pragma unroll
    for (int n = 0; n < 2; ++n) {
      f32x4 v = acc[m * 2 + n];
      int j = wc * 32 + n * 16 + (lane & 15);
#pragma unroll
      for (int r = 0; r < 4; ++r) {
        int t = wr * 32 + m * 16 + (lane >> 4) * 4 + r;
        Pl[t * 72 + j] = (j <= t) ? tobf(v[r]) : tobf(0.f);
      }
    }
  for (int nb = 0; nb < 8; ++nb) {
    __syncthreads();
    // stage V^T rows [nb*128, nb*128+128), padded stride 72
#pragma unroll
    for (int rr = 0; rr < 4; ++rr) {
      int row = rr * 32 + (tid >> 3);
      int j0 = (tid & 7) * 8;
      bf16x8 vv = *(const bf16x8*)(vT + ((size_t)c * VD + nb * 128 + row) * 64 + j0);
      *(bf16x8*)(sV + row * 72 + j0) = vv;
    }
    __syncthreads();
    f32x4 a2[8];
#pragma unroll
    for (int i = 0; i < 8; ++i) a2[i] = fzero();
#pragma unroll
    for (int ks = 0; ks < 64; ks += 32) {
      bf16x8 af[2], bfr[4];
#pragma unroll
      for (int m = 0; m < 2; ++m)
        af[m] = *(const bf16x8*)(Pl + (wr * 32 + m * 16 + (lane & 15)) * 72
                                 + ks + (lane >> 4) * 8);
#pragma unroll
      for (int n = 0; n < 4; ++n)
        bfr[n] = *(const bf16x8*)(sV + (wc * 64 + n * 16 + (lane & 15)) * 72
                                  + ks + (lane >> 4) * 8);
#pragma unroll
      for (int m = 0; m < 2; ++m)
#pragma unroll
        for (int n = 0; n < 4; ++n)
          a2[m * 4 + n] = __builtin_amdgcn_mfma_f32_16x16x32_bf16(
              af[m], bfr[n], a2[m * 4 + n], 0, 0, 0);
    }
#pragma unroll
    for (int m = 0; m < 2; ++m)
#pragma unroll
      for (int n = 0; n < 4; ++n) {
        int col = wc * 64 + n * 16 + (lane & 15);
#pragma unroll
        for (int r = 0; r < 4; ++r) {
          int row = wr * 32 + m * 16 + (lane >> 4) * 4 + r;
          attn[((size_t)c * CH + row) * VD + nb * 128 + col] = a2[m * 4 + n][r];
        }
      }
  }
}

// U^T[vv][kk] = sum_j V[j,vv] kbar[j,kk]  -> ustore slot (bf16)
__global__ __launch_bounds__(256) void k_ugemm(
    const bf16* __restrict__ vT, const bf16* __restrict__ kbarT,
    bf16* __restrict__ ustore, int g)
{
  __shared__ __align__(16) bf16 sA[3 * 128 * 32];
  __shared__ __align__(16) bf16 sB[3 * 128 * 32];
  const int cl = blockIdx.z, c = g * CPG + cl;
  const int m0 = blockIdx.x * 128, n0 = blockIdx.y * 128;
  const int tid = threadIdx.x, lane = tid & 63;
  const int wr = (tid >> 6) >> 1, wc = (tid >> 6) & 1;
  f32x4 acc[16];
#pragma unroll
  for (int i = 0; i < 16; ++i) acc[i] = fzero();
  gemm_core<128, 128>(vT + (size_t)c * VD * 64, 64, m0,
                      kbarT + (size_t)c * KD * 64, 64, n0, 64, acc, sA, sB, tid);
  bf16* dst = ustore + (size_t)cl * KD * VD;
#pragma unroll
  for (int m = 0; m < 4; ++m)
#pragma unroll
    for (int n = 0; n < 4; ++n) {
      f32x4 v = acc[m * 4 + n];
      int col = wc * 64 + n * 16 + (lane & 15);
#pragma unroll
      for (int r = 0; r < 4; ++r) {
        int row = wr * 64 + m * 16 + (lane >> 4) * 4 + r;
        dst[(size_t)(m0 + row) * KD + n0 + col] = tobf(v[r]);
      }
    }
}

// elementwise scan over chunks (in place: slot c becomes state AFTER chunk c)
__global__ __launch_bounds__(256) void k_scan(
    bf16* __restrict__ ustore, const float* __restrict__ la,
    float* __restrict__ Sinit, bf16* __restrict__ ScarryB,
    float* __restrict__ dstate, int g)
{
  __shared__ float tl[64][65];
  const int vv0 = blockIdx.x * 64, kk0 = blockIdx.y * 64;
  const int tid = threadIdx.x;
  const int col = tid & 63;       // kk local
  const int r0 = tid >> 6;        // 0..3 (vv local base)
  const int kk = kk0 + col;
  float s[16];
  if (g == 0) {
#pragma unroll
    for (int i = 0; i < 16; ++i) s[i] = 0.f;
  } else {
#pragma unroll
    for (int i = 0; i < 16; ++i)
      s[i] = Sinit[(size_t)(vv0 + r0 + 4 * i) * KD + kk];
  }
  for (int cl = 0; cl < CPG; ++cl) {
    int c = g * CPG + cl;
    float d = expf(la[(size_t)(c * CH + 63) * KD + kk]);
    size_t base = (size_t)cl * KD * VD;
#pragma unroll
    for (int i = 0; i < 16; ++i) {
      size_t idx = base + (size_t)(vv0 + r0 + 4 * i) * KD + kk;
      float u = (float)ustore[idx];
      s[i] = fmaf(d, s[i], u);
      ustore[idx] = tobf(s[i]);
    }
  }
  if (g < NGROUP - 1) {
#pragma unroll
    for (int i = 0; i < 16; ++i) {
      size_t o = (size_t)(vv0 + r0 + 4 * i) * KD + kk;
      Sinit[o] = s[i];
      ScarryB[o] = tobf(s[i]);
    }
  } else {
    // final state -> d_out (transpose [vv][kk] -> [kk][vv] via LDS)
#pragma unroll
    for (int i = 0; i < 16; ++i) tl[r0 + 4 * i][col] = s[i];
    __syncthreads();
#pragma unroll
    for (int i = 0; i < 16; ++i) {
      int kr = r0 + 4 * i;
      dstate[(size_t)(kk0 + kr) * VD + vv0 + col] = tl[col][kr];
    }
  }
}

// out_inter = q~_c @ S_{c-1}; accumulate into attn
__global__ __launch_bounds__(256) void k_inter(
    const bf16* __restrict__ qt, const bf16* __restrict__ ustore,
    const bf16* __restrict__ ScarryB, float* __restrict__ attn, int g)
{
  const int cl = blockIdx.y, c = g * CPG + cl;
  if (c == 0) return;  // S_{-1} = 0
  __shared__ __align__(16) bf16 sA[3 * 64 * 32];
  __shared__ __align__(16) bf16 sB[3 * 128 * 32];
  const bf16* B = (cl == 0) ? ScarryB : ustore + (size_t)(cl - 1) * KD * VD;
  const int n0 = blockIdx.x * 128;
  const int tid = threadIdx.x, lane = tid & 63;
  const int wr = (tid >> 6) >> 1, wc = (tid >> 6) & 1;
  f32x4 acc[8];
#pragma unroll
  for (int i = 0; i < 8; ++i) acc[i] = fzero();
  gemm_core<64, 128>(qt + (size_t)c * CH * KD, KD, 0, B, KD, n0, KD,
                     acc, sA, sB, tid);
#pragma unroll
  for (int m = 0; m < 2; ++m)
#pragma unroll
    for (int n = 0; n < 4; ++n) {
      f32x4 v = acc[m * 4 + n];
      int col = wc * 64 + n * 16 + (lane & 15);
#pragma unroll
      for (int r = 0; r < 4; ++r) {
        int row = wr * 32 + m * 16 + (lane >> 4) * 4 + r;
        attn[((size_t)c * CH + row) * VD + n0 + col] += v[r];
      }
    }
}

// y = attn_bf16 @ Wo^T + bo
__global__ __launch_bounds__(256) void k_out(
    const bf16* __restrict__ ob, const bf16* __restrict__ Wob,
    const float* __restrict__ bo, float* __restrict__ out)
{
  __shared__ __align__(16) bf16 sA[3 * 128 * 32];
  __shared__ __align__(16) bf16 sB[3 * 128 * 32];
  const int m0 = blockIdx.x * 128, n0 = blockIdx.y * 128;
  const int tid = threadIdx.x, lane = tid & 63;
  const int wr = (tid >> 6) >> 1, wc = (tid >> 6) & 1;
  f32x4 acc[16];
#pragma unroll
  for (int i = 0; i < 16; ++i) acc[i] = fzero();
  gemm_core<128, 128>(ob, VD, m0, Wob, VD, n0, VD, acc, sA, sB, tid);
#pragma unroll
  for (int m = 0; m < 4; ++m)
#pragma unroll
    for (int n = 0; n < 4; ++n) {
      f32x4 v = acc[m * 4 + n];
      int col = n0 + wc * 64 + n * 16 + (lane & 15);
      float b = bo[col];
#pragma unroll
      for (int r = 0; r < 4; ++r) {
        int row = m0 + wr * 64 + m * 16 + (lane >> 4) * 4 + r;
        out[(size_t)row * OD + col] = v[r] + b;
      }
    }
}

// ---------------------------------------------------------------------------
extern "C" void kernel_launch(void* const* d_in, const int* in_sizes, int n_in,
                              void* d_out, int out_size, void* d_ws, size_t ws_size,
                              hipStream_t stream)
{
  const float* hs = (const float*)d_in[0];
  const float* Wq = (const float*)d_in[1];
  const float* bq = (const float*)d_in[2];
  const float* Wk = (const float*)d_in[3];
  const float* bk = (const float*)d_in[4];
  const float* Wv = (const float*)d_in[5];
  const float* bv = (const float*)d_in[6];
  const float* Wg = (const float*)d_in[7];
  const float* bg = (const float*)d_in[8];
  const float* Wo = (const float*)d_in[9];
  const float* bo = (const float*)d_in[10];
  float* out = (float*)d_out;
  float* dstate = out + (size_t)T_ * OD;

  char* p = (char*)d_ws;
  auto alloc = [&](size_t b) -> char* {
    char* r = p; p += (b + 255) & ~(size_t)255; return r;
  };
  bf16* hsb    = (bf16*)alloc((size_t)T_ * H_ * 2);
  bf16* Wqb    = (bf16*)alloc((size_t)KD * H_ * 2);
  bf16* Wkb    = (bf16*)alloc((size_t)KD * H_ * 2);
  bf16* Wgb    = (bf16*)alloc((size_t)KD * H_ * 2);
  bf16* Wvb    = (bf16*)alloc((size_t)VD * H_ * 2);
  bf16* Wob    = (bf16*)alloc((size_t)OD * VD * 2);
  bf16* qb     = (bf16*)alloc((size_t)T_ * KD * 2);
  bf16* kb     = (bf16*)alloc((size_t)T_ * KD * 2);
  float* la    = (float*)alloc((size_t)T_ * KD * 4);
  bf16* vb     = (bf16*)alloc((size_t)T_ * VD * 2);
  bf16* qt     = (bf16*)alloc((size_t)T_ * KD * 2);
  bf16* kt     = (bf16*)alloc((size_t)T_ * KD * 2);
  bf16* kbarT  = (bf16*)alloc((size_t)T_ * KD * 2);
  bf16* vT     = (bf16*)alloc((size_t)T_ * VD * 2);
  float* attn  = (float*)alloc((size_t)T_ * VD * 4);
  bf16* ob     = (bf16*)alloc((size_t)T_ * VD * 2);
  float* Sinit = (float*)alloc((size_t)KD * VD * 4);
  bf16* ScarryB= (bf16*)alloc((size_t)KD * VD * 2);
  bf16* ustore = (bf16*)alloc((size_t)CPG * KD * VD * 2);
  if ((size_t)(p - (char*)d_ws) > ws_size) return;  // clean failure if ws too small

  // fp32 -> bf16 conversions (batched)
  k_cvt6<<<(int)((CVT_TOT / 4 + 255) / 256), 256, 0, stream>>>(
      hs, Wq, Wk, Wg, Wv, Wo, hsb, Wqb, Wkb, Wgb, Wvb, Wob);

  // projections + activations
  k_proj<<<dim3(T_ / 128, 32), 256, 0, stream>>>(
      hsb, Wqb, Wkb, Wgb, Wvb, bq, bk, bg, bv, qb, kb, la, vb);

  // cumsum(log g) within chunks
  k_cumsum<<<(NCHUNK * KD) / 256, 256, 0, stream>>>(la);

  // decay-weighted operands + transposes
  k_transform<<<dim3(16, NCHUNK, 2), 256, 0, stream>>>(
      qb, kb, la, vb, qt, kt, kbarT, vT);

  // intra-chunk attention -> attn
  k_intra<<<NCHUNK, 256, 0, stream>>>(qt, kt, vT, attn);

  // chunk summaries, state scan, inter-chunk contribution (2 groups)
  for (int g = 0; g < NGROUP; ++g) {
    k_ugemm<<<dim3(8, 8, CPG), 256, 0, stream>>>(vT, kbarT, ustore, g);
    k_scan<<<dim3(16, 16), 256, 0, stream>>>(ustore, la, Sinit, ScarryB, dstate, g);
    k_inter<<<dim3(8, CPG), 256, 0, stream>>>(qt, ustore, ScarryB, attn, g);
  }

  // output projection
  k_cvt<<<T_ * VD / 1024, 256, 0, stream>>>(attn, ob, T_ * VD);
  k_out<<<dim3(T_ / 128, OD / 128), 256, 0, stream>>>(ob, Wob, bo, out);
}

// Round 4
// 558.499 us; speedup vs baseline: 1.1798x; 1.1429x over previous
//
#include <hip/hip_runtime.h>
#include <stdint.h>
#include <stddef.h>

// ---------------------------------------------------------------------------
// SimpleRNN (gated linear attention) — chunked parallel formulation.
//   q = hs@Wq^T+bq ; k = sig(hs@Wk^T+bk) ; g = sig(hs@Wg^T+bg) ; v = hs@Wv^T+bv
//   S_t = diag(g_t) S_{t-1} + k_t v_t^T ; out_t = q_t S_t ; y = out@Wo^T+bo
// Chunked (C=64): la = within-chunk inclusive cumsum(log g)
//   q~ = q*exp(la), k~ = k*exp(-la), kbar = k*exp(laC-la)
//   out = tril(q~ k~^T) V  +  q~ @ S_prev
//   U_c = kbar^T V ;  S_c = exp(laC) (.) S_{c-1} + U_c   (elementwise scan)
//
// k_proj: 256x256-tile 8-wave deep pipeline (m201-class):
//   - K processed in 32-slices; ring of 4 LDS slice-buffers (128 KB total)
//   - LDS layout [chunk][row][16B] -> fragment ds_read_b128 is 4x contiguous
//     256B segments = ZERO bank conflicts (T2-equivalent by construction;
//     staged via per-lane pre-permuted global source, LDS dest lane-linear)
//   - 2 phases/slice, 16 MFMA each; per-phase barrier pair; setprio(1) (T5)
//   - counted s_waitcnt vmcnt(8) once per slice, never 0 mid-loop (T4)
// Other GEMMs keep the 128² 3-buf core (to be ported if this wins).
// ---------------------------------------------------------------------------

#define DEVI __device__ __forceinline__

typedef __bf16 bf16;
typedef __bf16 bf16x8 __attribute__((ext_vector_type(8)));
typedef __bf16 bf16x4 __attribute__((ext_vector_type(4)));
typedef float  f32x4  __attribute__((ext_vector_type(4)));

static constexpr int T_  = 4096;
static constexpr int H_  = 2048;
static constexpr int KD  = 1024;
static constexpr int VD  = 1024;
static constexpr int OD  = 2048;
static constexpr int CH  = 64;                 // chunk length
static constexpr int NCHUNK = T_ / CH;         // 64
static constexpr int NGROUP = 2;               // chunk groups (ws economy)
static constexpr int CPG    = NCHUNK / NGROUP; // 32

DEVI bf16 tobf(float f) {
  union { float f; uint32_t u; } x; x.f = f;
  uint32_t r = (x.u + 0x7FFFu + ((x.u >> 16) & 1u)) >> 16;  // RNE
  union { uint16_t s; bf16 b; } y; y.s = (uint16_t)r;
  return y.b;
}

DEVI f32x4 fzero() { f32x4 z = {0.f, 0.f, 0.f, 0.f}; return z; }

// async global->LDS, 16B per lane (lane-linear LDS destination).
DEVI void gld16(const bf16* g, bf16* l) {
  auto* g1 = reinterpret_cast<__attribute__((address_space(1))) uint32_t*>(
      (uintptr_t)g);
  auto* l3 = reinterpret_cast<__attribute__((address_space(3))) uint32_t*>(
      (uintptr_t)l);
  __builtin_amdgcn_global_load_lds(g1, l3, 16, 0, 0);
}

template<int N> DEVI void waitvm() {
  if constexpr (N == 0) asm volatile("s_waitcnt vmcnt(0)" ::: "memory");
  else if constexpr (N == 2) asm volatile("s_waitcnt vmcnt(2)" ::: "memory");
  else if constexpr (N == 3) asm volatile("s_waitcnt vmcnt(3)" ::: "memory");
  else if constexpr (N == 4) asm volatile("s_waitcnt vmcnt(4)" ::: "memory");
  else if constexpr (N == 8) asm volatile("s_waitcnt vmcnt(8)" ::: "memory");
  else static_assert(N == 0, "unsupported vmcnt");
}

// ===========================================================================
// 256x256 deep-pipeline GEMM core: C[m0..+256, n0..+256] = A@B^T (K templated)
// 512 threads = 8 waves (2Mx4N). acc[8][4] per thread.
// LDS slice slot (16KB/operand): elem offset = chunk*2048 + row*8, chunk=k/8.
// ===========================================================================
template<int K>
DEVI void gemm256_core(const bf16* __restrict__ A, int lda, int m0,
                       const bf16* __restrict__ B, int ldb, int n0,
                       f32x4 (*acc)[4], bf16* sA, bf16* sB, int tid)
{
  constexpr int NS = K / 32;          // number of 32-wide k slices
  const int lane = tid & 63;
  const int wid  = tid >> 6;
  const int wr   = wid >> 2;          // 0..1  (row half, 128 rows)
  const int wc   = wid & 3;           // 0..3  (col quarter, 64 cols)

  // staging source: thread covers (row = tid&255, chunks tid>>8 and 2+(tid>>8))
  const bf16* aRow = A + (size_t)(m0 + (tid & 255)) * lda + ((tid >> 8) << 3);
  const bf16* bRow = B + (size_t)(n0 + (tid & 255)) * ldb + ((tid >> 8) << 3);

  auto stA = [&](int s) {
    const int slot = s & 3;
    gld16(aRow + s * 32,      sA + slot * 8192 + tid * 8);
    gld16(aRow + s * 32 + 16, sA + slot * 8192 + tid * 8 + 4096);
  };
  auto stB = [&](int s) {
    const int slot = s & 3;
    gld16(bRow + s * 32,      sB + slot * 8192 + tid * 8);
    gld16(bRow + s * 32 + 16, sB + slot * 8192 + tid * 8 + 4096);
  };

  // fragment read base offsets (elements)
  const int aOff = ((lane >> 4) << 11) + ((wr * 128 + (lane & 15)) << 3);
  const int bOff = ((lane >> 4) << 11) + ((wc * 64  + (lane & 15)) << 3);

  // prologue: 3 slices in flight
  stA(0); stB(0); stA(1); stB(1); stA(2); stB(2);

  for (int s = 0; s < NS; ++s) {
    const int slot = s & 3;
    const bf16* pA = sA + slot * 8192;
    const bf16* pB = sB + slot * 8192;

    // ---- phase 0: B frags + A frags (m half 0), 16 MFMA ----
    waitvm<8>();                       // slice s landed (for this wave)
    __builtin_amdgcn_s_barrier();      // slice s landed for ALL waves
    __builtin_amdgcn_sched_barrier(0);
    bf16x8 bfr[4], af[4];
#pragma unroll
    for (int n = 0; n < 4; ++n)
      bfr[n] = *(const bf16x8*)(pB + bOff + n * 128);
#pragma unroll
    for (int m = 0; m < 4; ++m)
      af[m] = *(const bf16x8*)(pA + aOff + m * 128);
    if (s + 3 < NS) stA(s + 3);
    asm volatile("s_waitcnt lgkmcnt(0)" ::: "memory");
    __builtin_amdgcn_sched_barrier(0);
    __builtin_amdgcn_s_setprio(1);
#pragma unroll
    for (int m = 0; m < 4; ++m)
#pragma unroll
      for (int n = 0; n < 4; ++n)
        acc[m][n] = __builtin_amdgcn_mfma_f32_16x16x32_bf16(
            af[m], bfr[n], acc[m][n], 0, 0, 0);
    __builtin_amdgcn_s_setprio(0);
    __builtin_amdgcn_sched_barrier(0);
    __builtin_amdgcn_s_barrier();

    // ---- phase 1: A frags (m half 1), reuse B frags, 16 MFMA ----
    __builtin_amdgcn_sched_barrier(0);
#pragma unroll
    for (int m = 0; m < 4; ++m)
      af[m] = *(const bf16x8*)(pA + aOff + 512 + m * 128);
    if (s + 3 < NS) stB(s + 3);
    asm volatile("s_waitcnt lgkmcnt(0)" ::: "memory");
    __builtin_amdgcn_sched_barrier(0);
    __builtin_amdgcn_s_setprio(1);
#pragma unroll
    for (int m = 0; m < 4; ++m)
#pragma unroll
      for (int n = 0; n < 4; ++n)
        acc[4 + m][n] = __builtin_amdgcn_mfma_f32_16x16x32_bf16(
            af[m], bfr[n], acc[4 + m][n], 0, 0, 0);
    __builtin_amdgcn_s_setprio(0);
    __builtin_amdgcn_sched_barrier(0);
    __builtin_amdgcn_s_barrier();
  }
}

// ===========================================================================
// legacy 128² 3-buf core (still used by the small GEMMs)
// ===========================================================================
template<int BM, int BN>
DEVI void gemm_core(const bf16* A, int lda, int m0,
                    const bf16* B, int ldb, int n0,
                    int K, f32x4* acc, bf16* sA, bf16* sB, int tid)
{
  constexpr int MR = BM / 32;
  constexpr int NR = BN / 32;
  constexpr int ASZ = BM * 32;
  constexpr int BSZ = BN * 32;
  constexpr int LOADS = BM / 64 + BN / 64;
  const int lane = tid & 63;
  const int wr = (tid >> 6) >> 1;
  const int wc = (tid >> 6) & 1;
  const int srow = tid >> 2;
  const int skof = (tid & 3) * 8;
  const bf16* aB = A + (size_t)(m0 + srow) * lda + skof;
  const bf16* bB = B + (size_t)(n0 + srow) * ldb + skof;

  auto stage = [&](int t, int buf) {
    const int k0 = t * 32;
#pragma unroll
    for (int r = 0; r < BM / 64; ++r)
      gld16(aB + (size_t)r * 64 * lda + k0, sA + buf * ASZ + r * 2048 + tid * 8);
#pragma unroll
    for (int r = 0; r < BN / 64; ++r)
      gld16(bB + (size_t)r * 64 * ldb + k0, sB + buf * BSZ + r * 2048 + tid * 8);
  };

  const int nt = K / 32;
  stage(0, 0);
  if (nt > 1) stage(1, 1);
  int cur = 0;
  for (int t = 0; t < nt; ++t) {
    if (t < nt - 1) waitvm<LOADS>();
    else            waitvm<0>();
    __builtin_amdgcn_s_barrier();
    __builtin_amdgcn_sched_barrier(0);
    if (t + 2 < nt) {
      int b2 = cur + 2; if (b2 >= 3) b2 -= 3;
      stage(t + 2, b2);
    }
    const bf16* pA = sA + cur * ASZ;
    const bf16* pB = sB + cur * BSZ;
    bf16x8 af[MR], bfr[NR];
#pragma unroll
    for (int m = 0; m < MR; ++m)
      af[m] = *(const bf16x8*)(pA + (wr * (MR * 16) + m * 16 + (lane & 15)) * 32
                               + (lane >> 4) * 8);
#pragma unroll
    for (int n = 0; n < NR; ++n)
      bfr[n] = *(const bf16x8*)(pB + (wc * (NR * 16) + n * 16 + (lane & 15)) * 32
                                + (lane >> 4) * 8);
#pragma unroll
    for (int m = 0; m < MR; ++m)
#pragma unroll
      for (int n = 0; n < NR; ++n)
        acc[m * NR + n] = __builtin_amdgcn_mfma_f32_16x16x32_bf16(
            af[m], bfr[n], acc[m * NR + n], 0, 0, 0);
    ++cur; if (cur >= 3) cur -= 3;
  }
}

// ---------------------------------------------------------------------------
static constexpr size_t CVT_HS = (size_t)T_ * H_;
static constexpr size_t CVT_W  = (size_t)KD * H_;
static constexpr size_t CVT_WO = (size_t)OD * VD;
static constexpr size_t CVT_TOT = CVT_HS + 4 * CVT_W + CVT_WO;

__global__ __launch_bounds__(256) void k_cvt6(
    const float* __restrict__ hs, const float* __restrict__ Wq,
    const float* __restrict__ Wk, const float* __restrict__ Wg,
    const float* __restrict__ Wv, const float* __restrict__ Wo,
    bf16* __restrict__ hsb, bf16* __restrict__ Wqb,
    bf16* __restrict__ Wkb, bf16* __restrict__ Wgb,
    bf16* __restrict__ Wvb, bf16* __restrict__ Wob)
{
  size_t i = ((size_t)blockIdx.x * 256 + threadIdx.x) * 4;
  if (i >= CVT_TOT) return;
  const float* s; bf16* d; size_t off;
  if (i < CVT_HS)                { s = hs; d = hsb; off = i; }
  else if (i < CVT_HS + CVT_W)   { s = Wq; d = Wqb; off = i - CVT_HS; }
  else if (i < CVT_HS + 2*CVT_W) { s = Wk; d = Wkb; off = i - CVT_HS - CVT_W; }
  else if (i < CVT_HS + 3*CVT_W) { s = Wg; d = Wgb; off = i - CVT_HS - 2*CVT_W; }
  else if (i < CVT_HS + 4*CVT_W) { s = Wv; d = Wvb; off = i - CVT_HS - 3*CVT_W; }
  else                           { s = Wo; d = Wob; off = i - CVT_HS - 4*CVT_W; }
  float4 v = *(const float4*)(s + off);
  bf16x4 o; o[0] = tobf(v.x); o[1] = tobf(v.y); o[2] = tobf(v.z); o[3] = tobf(v.w);
  *(bf16x4*)(d + off) = o;
}

__global__ __launch_bounds__(256) void k_cvt(const float* __restrict__ in,
                                             bf16* __restrict__ out, int n) {
  int i = (blockIdx.x * 256 + threadIdx.x) * 4;
  if (i >= n) return;
  float4 v = *(const float4*)(in + i);
  bf16x4 o; o[0] = tobf(v.x); o[1] = tobf(v.y); o[2] = tobf(v.z); o[3] = tobf(v.w);
  *(bf16x4*)(out + i) = o;
}

// Projections via 256² core: N-tiles of 256 within [q|k|g|v] (seg = by>>2)
__global__ __launch_bounds__(512) void k_proj256(
    const bf16* __restrict__ hsb,
    const bf16* __restrict__ Wqb, const bf16* __restrict__ Wkb,
    const bf16* __restrict__ Wgb, const bf16* __restrict__ Wvb,
    const float* __restrict__ bq, const float* __restrict__ bk,
    const float* __restrict__ bg, const float* __restrict__ bv,
    bf16* __restrict__ qb, bf16* __restrict__ kb,
    float* __restrict__ la, bf16* __restrict__ vb)
{
  __shared__ __align__(16) bf16 sAB[8 * 8192];   // 128 KB: A ring 4x16KB, B ring
  bf16* sA = sAB;
  bf16* sB = sAB + 4 * 8192;
  const int m0 = blockIdx.x * 256;
  const int by = blockIdx.y;
  const int seg = by >> 2;                  // 0..3
  const int nseg0 = (by & 3) * 256;         // col base within segment
  const bf16* W = seg == 0 ? Wqb : seg == 1 ? Wkb : seg == 2 ? Wgb : Wvb;
  const float* bias = seg == 0 ? bq : seg == 1 ? bk : seg == 2 ? bg : bv;
  const int tid = threadIdx.x, lane = tid & 63;
  const int wid = tid >> 6, wr = wid >> 2, wc = wid & 3;

  f32x4 acc[8][4];
#pragma unroll
  for (int m = 0; m < 8; ++m)
#pragma unroll
    for (int n = 0; n < 4; ++n) acc[m][n] = fzero();

  gemm256_core<H_>(hsb, H_, m0, W, H_, nseg0, acc, sA, sB, tid);

#pragma unroll
  for (int m = 0; m < 8; ++m)
#pragma unroll
    for (int n = 0; n < 4; ++n) {
      f32x4 v = acc[m][n];
      int colSeg = nseg0 + wc * 64 + n * 16 + (lane & 15);
      float b = bias[colSeg];
#pragma unroll
      for (int r = 0; r < 4; ++r) {
        int row = m0 + wr * 128 + m * 16 + (lane >> 4) * 4 + r;
        float x = v[r] + b;
        size_t o = (size_t)row * KD + colSeg;
        if (seg == 0)      qb[o] = tobf(x);
        else if (seg == 1) kb[o] = tobf(1.f / (1.f + expf(-x)));
        else if (seg == 2) la[o] = fminf(x, 0.f) - log1pf(expf(-fabsf(x)));
        else               vb[o] = tobf(x);
      }
    }
}

// within-chunk inclusive cumsum of log g (in place)
__global__ __launch_bounds__(256) void k_cumsum(float* __restrict__ la) {
  int gid = blockIdx.x * 256 + threadIdx.x;
  int c = gid >> 10, kk = gid & 1023;
  size_t base = (size_t)c * CH * KD + kk;
  float s = 0.f;
  for (int i = 0; i < CH; ++i) {
    s += la[base + (size_t)i * KD];
    la[base + (size_t)i * KD] = s;
  }
}

// q~,k~ (t-major) ; kbar^T [c][kk][t] ; V^T [c][vv][t]
__global__ __launch_bounds__(256) void k_transform(
    const bf16* __restrict__ qb, const bf16* __restrict__ kb,
    const float* __restrict__ la, const bf16* __restrict__ vb,
    bf16* __restrict__ qt, bf16* __restrict__ kt,
    bf16* __restrict__ kbarT, bf16* __restrict__ vT)
{
  __shared__ bf16 tr[64][72];
  const int c = blockIdx.y, tile = blockIdx.x, path = blockIdx.z;
  const int tid = threadIdx.x;
  const int colL = tid & 63;
  const int rbase = tid >> 6;
  if (path == 0) {
    const int kk0 = tile * 64;
    const int kk = kk0 + colL;
    const float lc = la[(size_t)(c * CH + 63) * KD + kk];
#pragma unroll
    for (int i = 0; i < 16; ++i) {
      int tl = rbase + 4 * i;
      size_t idx = (size_t)(c * CH + tl) * KD + kk;
      float lav = la[idx];
      float qv = (float)qb[idx];
      float kv = (float)kb[idx];
      qt[idx] = tobf(qv * expf(lav));
      kt[idx] = tobf(kv * expf(-lav));
      tr[colL][tl] = tobf(kv * expf(lc - lav));
    }
    __syncthreads();
#pragma unroll
    for (int i = 0; i < 16; ++i) {
      int row = rbase + 4 * i;
      kbarT[((size_t)c * KD + kk0 + row) * 64 + colL] = tr[row][colL];
    }
  } else {
    const int vv0 = tile * 64;
#pragma unroll
    for (int i = 0; i < 16; ++i) {
      int tl = rbase + 4 * i;
      tr[colL][tl] = vb[(size_t)(c * CH + tl) * VD + vv0 + colL];
    }
    __syncthreads();
#pragma unroll
    for (int i = 0; i < 16; ++i) {
      int row = rbase + 4 * i;
      vT[((size_t)c * VD + vv0 + row) * 64 + colL] = tr[row][colL];
    }
  }
}

// intra-chunk: P = tril(q~ k~^T) (64x64), out_intra = P @ V -> attn (fp32)
__global__ __launch_bounds__(256) void k_intra(
    const bf16* __restrict__ qt, const bf16* __restrict__ kt,
    const bf16* __restrict__ vT, float* __restrict__ attn)
{
  __shared__ __align__(16) bf16 sA[3 * 64 * 32];
  __shared__ __align__(16) bf16 sB[3 * 64 * 32];
  __shared__ __align__(16) bf16 sV[128 * 72];
  __shared__ __align__(16) bf16 Pl[64 * 72];
  const int c = blockIdx.x;
  const int tid = threadIdx.x, lane = tid & 63;
  const int wr = (tid >> 6) >> 1, wc = (tid >> 6) & 1;
  f32x4 acc[4];
#pragma unroll
  for (int i = 0; i < 4; ++i) acc[i] = fzero();
  gemm_core<64, 64>(qt + (size_t)c * CH * KD, KD, 0,
                    kt + (size_t)c * CH * KD, KD, 0, KD, acc, sA, sB, tid);
#pragma unroll
  for (int m = 0; m < 2; ++m)
#pragma unroll
    for (int n = 0; n < 2; ++n) {
      f32x4 v = acc[m * 2 + n];
      int j = wc * 32 + n * 16 + (lane & 15);
#pragma unroll
      for (int r = 0; r < 4; ++r) {
        int t = wr * 32 + m * 16 + (lane >> 4) * 4 + r;
        Pl[t * 72 + j] = (j <= t) ? tobf(v[r]) : tobf(0.f);
      }
    }
  for (int nb = 0; nb < 8; ++nb) {
    __syncthreads();
#pragma unroll
    for (int rr = 0; rr < 4; ++rr) {
      int row = rr * 32 + (tid >> 3);
      int j0 = (tid & 7) * 8;
      bf16x8 vv = *(const bf16x8*)(vT + ((size_t)c * VD + nb * 128 + row) * 64 + j0);
      *(bf16x8*)(sV + row * 72 + j0) = vv;
    }
    __syncthreads();
    f32x4 a2[8];
#pragma unroll
    for (int i = 0; i < 8; ++i) a2[i] = fzero();
#pragma unroll
    for (int ks = 0; ks < 64; ks += 32) {
      bf16x8 af[2], bfr[4];
#pragma unroll
      for (int m = 0; m < 2; ++m)
        af[m] = *(const bf16x8*)(Pl + (wr * 32 + m * 16 + (lane & 15)) * 72
                                 + ks + (lane >> 4) * 8);
#pragma unroll
      for (int n = 0; n < 4; ++n)
        bfr[n] = *(const bf16x8*)(sV + (wc * 64 + n * 16 + (lane & 15)) * 72
                                  + ks + (lane >> 4) * 8);
#pragma unroll
      for (int m = 0; m < 2; ++m)
#pragma unroll
        for (int n = 0; n < 4; ++n)
          a2[m * 4 + n] = __builtin_amdgcn_mfma_f32_16x16x32_bf16(
              af[m], bfr[n], a2[m * 4 + n], 0, 0, 0);
    }
#pragma unroll
    for (int m = 0; m < 2; ++m)
#pragma unroll
      for (int n = 0; n < 4; ++n) {
        int col = wc * 64 + n * 16 + (lane & 15);
#pragma unroll
        for (int r = 0; r < 4; ++r) {
          int row = wr * 32 + m * 16 + (lane >> 4) * 4 + r;
          attn[((size_t)c * CH + row) * VD + nb * 128 + col] = a2[m * 4 + n][r];
        }
      }
  }
}

// U^T[vv][kk] = sum_j V[j,vv] kbar[j,kk]  -> ustore slot (bf16)
__global__ __launch_bounds__(256) void k_ugemm(
    const bf16* __restrict__ vT, const bf16* __restrict__ kbarT,
    bf16* __restrict__ ustore, int g)
{
  __shared__ __align__(16) bf16 sA[3 * 128 * 32];
  __shared__ __align__(16) bf16 sB[3 * 128 * 32];
  const int cl = blockIdx.z, c = g * CPG + cl;
  const int m0 = blockIdx.x * 128, n0 = blockIdx.y * 128;
  const int tid = threadIdx.x, lane = tid & 63;
  const int wr = (tid >> 6) >> 1, wc = (tid >> 6) & 1;
  f32x4 acc[16];
#pragma unroll
  for (int i = 0; i < 16; ++i) acc[i] = fzero();
  gemm_core<128, 128>(vT + (size_t)c * VD * 64, 64, m0,
                      kbarT + (size_t)c * KD * 64, 64, n0, 64, acc, sA, sB, tid);
  bf16* dst = ustore + (size_t)cl * KD * VD;
#pragma unroll
  for (int m = 0; m < 4; ++m)
#pragma unroll
    for (int n = 0; n < 4; ++n) {
      f32x4 v = acc[m * 4 + n];
      int col = wc * 64 + n * 16 + (lane & 15);
#pragma unroll
      for (int r = 0; r < 4; ++r) {
        int row = wr * 64 + m * 16 + (lane >> 4) * 4 + r;
        dst[(size_t)(m0 + row) * KD + n0 + col] = tobf(v[r]);
      }
    }
}

// elementwise scan over chunks — vectorized bf16x8 (8 kk per thread)
// block: 64 vv x 128 kk.  grid (VD/64=16, KD/128=8)
__global__ __launch_bounds__(256) void k_scan(
    bf16* __restrict__ ustore, const float* __restrict__ la,
    float* __restrict__ Sinit, bf16* __restrict__ ScarryB,
    float* __restrict__ dstate, int g)
{
  __shared__ float tl[64][132];
  const int vv0 = blockIdx.x * 64, kk0 = blockIdx.y * 128;
  const int tid = threadIdx.x;
  const int kv = (tid & 15) * 8;       // kk offset within 128
  const int vr = tid >> 4;             // 0..15; rows vr, vr+16, vr+32, vr+48
  float s[4][8];
  if (g == 0) {
#pragma unroll
    for (int i = 0; i < 4; ++i)
#pragma unroll
      for (int j = 0; j < 8; ++j) s[i][j] = 0.f;
  } else {
#pragma unroll
    for (int i = 0; i < 4; ++i) {
      const float* p = Sinit + (size_t)(vv0 + vr + 16 * i) * KD + kk0 + kv;
      float4 a = *(const float4*)p, b = *(const float4*)(p + 4);
      s[i][0]=a.x; s[i][1]=a.y; s[i][2]=a.z; s[i][3]=a.w;
      s[i][4]=b.x; s[i][5]=b.y; s[i][6]=b.z; s[i][7]=b.w;
    }
  }
  for (int cl = 0; cl < CPG; ++cl) {
    int c = g * CPG + cl;
    const float* lp = la + (size_t)(c * CH + 63) * KD + kk0 + kv;
    float4 la0 = *(const float4*)lp, la1 = *(const float4*)(lp + 4);
    float d[8] = {expf(la0.x), expf(la0.y), expf(la0.z), expf(la0.w),
                  expf(la1.x), expf(la1.y), expf(la1.z), expf(la1.w)};
    size_t base = (size_t)cl * KD * VD;
#pragma unroll
    for (int i = 0; i < 4; ++i) {
      bf16* up = ustore + base + (size_t)(vv0 + vr + 16 * i) * KD + kk0 + kv;
      bf16x8 u = *(const bf16x8*)up;
      bf16x8 o;
#pragma unroll
      for (int j = 0; j < 8; ++j) {
        s[i][j] = fmaf(d[j], s[i][j], (float)u[j]);
        o[j] = tobf(s[i][j]);
      }
      *(bf16x8*)up = o;
    }
  }
  if (g < NGROUP - 1) {
#pragma unroll
    for (int i = 0; i < 4; ++i) {
      float* p = Sinit + (size_t)(vv0 + vr + 16 * i) * KD + kk0 + kv;
      bf16* pb = ScarryB + (size_t)(vv0 + vr + 16 * i) * KD + kk0 + kv;
      float4 a = {s[i][0], s[i][1], s[i][2], s[i][3]};
      float4 b = {s[i][4], s[i][5], s[i][6], s[i][7]};
      *(float4*)p = a; *(float4*)(p + 4) = b;
      bf16x8 o;
#pragma unroll
      for (int j = 0; j < 8; ++j) o[j] = tobf(s[i][j]);
      *(bf16x8*)pb = o;
    }
  } else {
    // final state -> d_out, transposed to [kk][vv] via LDS
#pragma unroll
    for (int i = 0; i < 4; ++i)
#pragma unroll
      for (int j = 0; j < 8; ++j) tl[vr + 16 * i][kv + j] = s[i][j];
    __syncthreads();
    const int kkL = tid >> 1;            // 0..127
    const int vvh = (tid & 1) * 32;      // half of 64 vv
    float* dp = dstate + (size_t)(kk0 + kkL) * VD + vv0 + vvh;
#pragma unroll
    for (int j4 = 0; j4 < 8; ++j4) {
      float4 o2 = {tl[vvh + j4 * 4 + 0][kkL], tl[vvh + j4 * 4 + 1][kkL],
                   tl[vvh + j4 * 4 + 2][kkL], tl[vvh + j4 * 4 + 3][kkL]};
      *(float4*)(dp + j4 * 4) = o2;
    }
  }
}

// out_inter = q~_c @ S_{c-1}; accumulate into attn
__global__ __launch_bounds__(256) void k_inter(
    const bf16* __restrict__ qt, const bf16* __restrict__ ustore,
    const bf16* __restrict__ ScarryB, float* __restrict__ attn, int g)
{
  const int cl = blockIdx.y, c = g * CPG + cl;
  if (c == 0) return;
  __shared__ __align__(16) bf16 sA[3 * 64 * 32];
  __shared__ __align__(16) bf16 sB[3 * 128 * 32];
  const bf16* B = (cl == 0) ? ScarryB : ustore + (size_t)(cl - 1) * KD * VD;
  const int n0 = blockIdx.x * 128;
  const int tid = threadIdx.x, lane = tid & 63;
  const int wr = (tid >> 6) >> 1, wc = (tid >> 6) & 1;
  f32x4 acc[8];
#pragma unroll
  for (int i = 0; i < 8; ++i) acc[i] = fzero();
  gemm_core<64, 128>(qt + (size_t)c * CH * KD, KD, 0, B, KD, n0, KD,
                     acc, sA, sB, tid);
#pragma unroll
  for (int m = 0; m < 2; ++m)
#pragma unroll
    for (int n = 0; n < 4; ++n) {
      f32x4 v = acc[m * 4 + n];
      int col = wc * 64 + n * 16 + (lane & 15);
#pragma unroll
      for (int r = 0; r < 4; ++r) {
        int row = wr * 32 + m * 16 + (lane >> 4) * 4 + r;
        attn[((size_t)c * CH + row) * VD + n0 + col] += v[r];
      }
    }
}

// y = attn_bf16 @ Wo^T + bo
__global__ __launch_bounds__(256) void k_out(
    const bf16* __restrict__ ob, const bf16* __restrict__ Wob,
    const float* __restrict__ bo, float* __restrict__ out)
{
  __shared__ __align__(16) bf16 sA[3 * 128 * 32];
  __shared__ __align__(16) bf16 sB[3 * 128 * 32];
  const int m0 = blockIdx.x * 128, n0 = blockIdx.y * 128;
  const int tid = threadIdx.x, lane = tid & 63;
  const int wr = (tid >> 6) >> 1, wc = (tid >> 6) & 1;
  f32x4 acc[16];
#pragma unroll
  for (int i = 0; i < 16; ++i) acc[i] = fzero();
  gemm_core<128, 128>(ob, VD, m0, Wob, VD, n0, VD, acc, sA, sB, tid);
#pragma unroll
  for (int m = 0; m < 4; ++m)
#pragma unroll
    for (int n = 0; n < 4; ++n) {
      f32x4 v = acc[m * 4 + n];
      int col = n0 + wc * 64 + n * 16 + (lane & 15);
      float b = bo[col];
#pragma unroll
      for (int r = 0; r < 4; ++r) {
        int row = m0 + wr * 64 + m * 16 + (lane >> 4) * 4 + r;
        out[(size_t)row * OD + col] = v[r] + b;
      }
    }
}

// ---------------------------------------------------------------------------
extern "C" void kernel_launch(void* const* d_in, const int* in_sizes, int n_in,
                              void* d_out, int out_size, void* d_ws, size_t ws_size,
                              hipStream_t stream)
{
  const float* hs = (const float*)d_in[0];
  const float* Wq = (const float*)d_in[1];
  const float* bq = (const float*)d_in[2];
  const float* Wk = (const float*)d_in[3];
  const float* bk = (const float*)d_in[4];
  const float* Wv = (const float*)d_in[5];
  const float* bv = (const float*)d_in[6];
  const float* Wg = (const float*)d_in[7];
  const float* bg = (const float*)d_in[8];
  const float* Wo = (const float*)d_in[9];
  const float* bo = (const float*)d_in[10];
  float* out = (float*)d_out;
  float* dstate = out + (size_t)T_ * OD;

  char* p = (char*)d_ws;
  auto alloc = [&](size_t b) -> char* {
    char* r = p; p += (b + 255) & ~(size_t)255; return r;
  };
  bf16* hsb    = (bf16*)alloc((size_t)T_ * H_ * 2);
  bf16* Wqb    = (bf16*)alloc((size_t)KD * H_ * 2);
  bf16* Wkb    = (bf16*)alloc((size_t)KD * H_ * 2);
  bf16* Wgb    = (bf16*)alloc((size_t)KD * H_ * 2);
  bf16* Wvb    = (bf16*)alloc((size_t)VD * H_ * 2);
  bf16* Wob    = (bf16*)alloc((size_t)OD * VD * 2);
  bf16* qb     = (bf16*)alloc((size_t)T_ * KD * 2);
  bf16* kb     = (bf16*)alloc((size_t)T_ * KD * 2);
  float* la    = (float*)alloc((size_t)T_ * KD * 4);
  bf16* vb     = (bf16*)alloc((size_t)T_ * VD * 2);
  bf16* qt     = (bf16*)alloc((size_t)T_ * KD * 2);
  bf16* kt     = (bf16*)alloc((size_t)T_ * KD * 2);
  bf16* kbarT  = (bf16*)alloc((size_t)T_ * KD * 2);
  bf16* vT     = (bf16*)alloc((size_t)T_ * VD * 2);
  float* attn  = (float*)alloc((size_t)T_ * VD * 4);
  bf16* ob     = (bf16*)alloc((size_t)T_ * VD * 2);
  float* Sinit = (float*)alloc((size_t)KD * VD * 4);
  bf16* ScarryB= (bf16*)alloc((size_t)KD * VD * 2);
  bf16* ustore = (bf16*)alloc((size_t)CPG * KD * VD * 2);
  if ((size_t)(p - (char*)d_ws) > ws_size) return;

  k_cvt6<<<(int)((CVT_TOT / 4 + 255) / 256), 256, 0, stream>>>(
      hs, Wq, Wk, Wg, Wv, Wo, hsb, Wqb, Wkb, Wgb, Wvb, Wob);

  // projections + activations (256² deep-pipeline core)
  k_proj256<<<dim3(T_ / 256, 16), 512, 0, stream>>>(
      hsb, Wqb, Wkb, Wgb, Wvb, bq, bk, bg, bv, qb, kb, la, vb);

  k_cumsum<<<(NCHUNK * KD) / 256, 256, 0, stream>>>(la);

  k_transform<<<dim3(16, NCHUNK, 2), 256, 0, stream>>>(
      qb, kb, la, vb, qt, kt, kbarT, vT);

  k_intra<<<NCHUNK, 256, 0, stream>>>(qt, kt, vT, attn);

  for (int g = 0; g < NGROUP; ++g) {
    k_ugemm<<<dim3(8, 8, CPG), 256, 0, stream>>>(vT, kbarT, ustore, g);
    k_scan<<<dim3(16, 8), 256, 0, stream>>>(ustore, la, Sinit, ScarryB, dstate, g);
    k_inter<<<dim3(8, CPG), 256, 0, stream>>>(qt, ustore, ScarryB, attn, g);
  }

  k_cvt<<<T_ * VD / 1024, 256, 0, stream>>>(attn, ob, T_ * VD);
  k_out<<<dim3(T_ / 128, OD / 128), 256, 0, stream>>>(ob, Wob, bo, out);
}

// Round 5
// 476.195 us; speedup vs baseline: 1.3837x; 1.1728x over previous
//
#include <hip/hip_runtime.h>
#include <stdint.h>
#include <stddef.h>

// ---------------------------------------------------------------------------
// SimpleRNN (gated linear attention) — chunked parallel formulation.
//   q = hs@Wq^T+bq ; k = sig(hs@Wk^T+bk) ; g = sig(hs@Wg^T+bg) ; v = hs@Wv^T+bv
//   S_t = diag(g_t) S_{t-1} + k_t v_t^T ; out_t = q_t S_t ; y = out@Wo^T+bo
// Chunked (C=64): la = within-chunk inclusive cumsum(log g)  [fused into
//   k_transform], q~ = q*exp(la), k~ = k*exp(-la), kbar = k*exp(laC-la)
//   out = tril(q~ k~^T) V  +  q~ @ S_prev
//   U_c = kbar^T V ;  S_c = exp(laC) (.) S_{c-1} + U_c   (elementwise scan)
// GEMM core: 128² 3-buffer counted pipeline (empirically the best of the
// structures tried: R1 1-buf == R2 2-buf == R3 3-buf == 183us for k_proj;
// R4 256² deep pipeline regressed to 270us at 1 block/CU).
// ---------------------------------------------------------------------------

#define DEVI __device__ __forceinline__

typedef __bf16 bf16;
typedef __bf16 bf16x8 __attribute__((ext_vector_type(8)));
typedef __bf16 bf16x4 __attribute__((ext_vector_type(4)));
typedef float  f32x4  __attribute__((ext_vector_type(4)));

static constexpr int T_  = 4096;
static constexpr int H_  = 2048;
static constexpr int KD  = 1024;
static constexpr int VD  = 1024;
static constexpr int OD  = 2048;
static constexpr int CH  = 64;                 // chunk length
static constexpr int NCHUNK = T_ / CH;         // 64
static constexpr int NGROUP = 2;               // chunk groups (ws economy)
static constexpr int CPG    = NCHUNK / NGROUP; // 32

DEVI bf16 tobf(float f) {
  union { float f; uint32_t u; } x; x.f = f;
  uint32_t r = (x.u + 0x7FFFu + ((x.u >> 16) & 1u)) >> 16;  // RNE
  union { uint16_t s; bf16 b; } y; y.s = (uint16_t)r;
  return y.b;
}

DEVI f32x4 fzero() { f32x4 z = {0.f, 0.f, 0.f, 0.f}; return z; }

// async global->LDS, 16B per lane (lane-linear LDS destination).
DEVI void gld16(const bf16* g, bf16* l) {
  auto* g1 = reinterpret_cast<__attribute__((address_space(1))) uint32_t*>(
      (uintptr_t)g);
  auto* l3 = reinterpret_cast<__attribute__((address_space(3))) uint32_t*>(
      (uintptr_t)l);
  __builtin_amdgcn_global_load_lds(g1, l3, 16, 0, 0);
}

template<int N> DEVI void waitvm() {
  if constexpr (N == 0) asm volatile("s_waitcnt vmcnt(0)" ::: "memory");
  else if constexpr (N == 2) asm volatile("s_waitcnt vmcnt(2)" ::: "memory");
  else if constexpr (N == 3) asm volatile("s_waitcnt vmcnt(3)" ::: "memory");
  else if constexpr (N == 4) asm volatile("s_waitcnt vmcnt(4)" ::: "memory");
  else static_assert(N == 0, "unsupported vmcnt");
}

// C[m0..+BM, n0..+BN] += A[M,K] * B[N,K]^T, both row-major K-contiguous.
// 4 waves in 2x2; per wave MR x NR 16x16 frags; BK=32; 3-buffer counted
// pipeline (see R3 notes).
template<int BM, int BN>
DEVI void gemm_core(const bf16* A, int lda, int m0,
                    const bf16* B, int ldb, int n0,
                    int K, f32x4* acc, bf16* sA, bf16* sB, int tid)
{
  constexpr int MR = BM / 32;
  constexpr int NR = BN / 32;
  constexpr int ASZ = BM * 32;
  constexpr int BSZ = BN * 32;
  constexpr int LOADS = BM / 64 + BN / 64;
  const int lane = tid & 63;
  const int wr = (tid >> 6) >> 1;
  const int wc = (tid >> 6) & 1;
  const int srow = tid >> 2;
  const int skof = (tid & 3) * 8;
  const bf16* aB = A + (size_t)(m0 + srow) * lda + skof;
  const bf16* bB = B + (size_t)(n0 + srow) * ldb + skof;

  auto stage = [&](int t, int buf) {
    const int k0 = t * 32;
#pragma unroll
    for (int r = 0; r < BM / 64; ++r)
      gld16(aB + (size_t)r * 64 * lda + k0, sA + buf * ASZ + r * 2048 + tid * 8);
#pragma unroll
    for (int r = 0; r < BN / 64; ++r)
      gld16(bB + (size_t)r * 64 * ldb + k0, sB + buf * BSZ + r * 2048 + tid * 8);
  };

  const int nt = K / 32;
  stage(0, 0);
  if (nt > 1) stage(1, 1);
  int cur = 0;
  for (int t = 0; t < nt; ++t) {
    if (t < nt - 1) waitvm<LOADS>();
    else            waitvm<0>();
    __builtin_amdgcn_s_barrier();
    __builtin_amdgcn_sched_barrier(0);
    if (t + 2 < nt) {
      int b2 = cur + 2; if (b2 >= 3) b2 -= 3;
      stage(t + 2, b2);
    }
    const bf16* pA = sA + cur * ASZ;
    const bf16* pB = sB + cur * BSZ;
    bf16x8 af[MR], bfr[NR];
#pragma unroll
    for (int m = 0; m < MR; ++m)
      af[m] = *(const bf16x8*)(pA + (wr * (MR * 16) + m * 16 + (lane & 15)) * 32
                               + (lane >> 4) * 8);
#pragma unroll
    for (int n = 0; n < NR; ++n)
      bfr[n] = *(const bf16x8*)(pB + (wc * (NR * 16) + n * 16 + (lane & 15)) * 32
                                + (lane >> 4) * 8);
#pragma unroll
    for (int m = 0; m < MR; ++m)
#pragma unroll
      for (int n = 0; n < NR; ++n)
        acc[m * NR + n] = __builtin_amdgcn_mfma_f32_16x16x32_bf16(
            af[m], bfr[n], acc[m * NR + n], 0, 0, 0);
    ++cur; if (cur >= 3) cur -= 3;
  }
}

// ---------------------------------------------------------------------------
static constexpr size_t CVT_HS = (size_t)T_ * H_;
static constexpr size_t CVT_W  = (size_t)KD * H_;
static constexpr size_t CVT_WO = (size_t)OD * VD;
static constexpr size_t CVT_TOT = CVT_HS + 4 * CVT_W + CVT_WO;

__global__ __launch_bounds__(256) void k_cvt6(
    const float* __restrict__ hs, const float* __restrict__ Wq,
    const float* __restrict__ Wk, const float* __restrict__ Wg,
    const float* __restrict__ Wv, const float* __restrict__ Wo,
    bf16* __restrict__ hsb, bf16* __restrict__ Wqb,
    bf16* __restrict__ Wkb, bf16* __restrict__ Wgb,
    bf16* __restrict__ Wvb, bf16* __restrict__ Wob)
{
  size_t i = ((size_t)blockIdx.x * 256 + threadIdx.x) * 4;
  if (i >= CVT_TOT) return;
  const float* s; bf16* d; size_t off;
  if (i < CVT_HS)                { s = hs; d = hsb; off = i; }
  else if (i < CVT_HS + CVT_W)   { s = Wq; d = Wqb; off = i - CVT_HS; }
  else if (i < CVT_HS + 2*CVT_W) { s = Wk; d = Wkb; off = i - CVT_HS - CVT_W; }
  else if (i < CVT_HS + 3*CVT_W) { s = Wg; d = Wgb; off = i - CVT_HS - 2*CVT_W; }
  else if (i < CVT_HS + 4*CVT_W) { s = Wv; d = Wvb; off = i - CVT_HS - 3*CVT_W; }
  else                           { s = Wo; d = Wob; off = i - CVT_HS - 4*CVT_W; }
  float4 v = *(const float4*)(s + off);
  bf16x4 o; o[0] = tobf(v.x); o[1] = tobf(v.y); o[2] = tobf(v.z); o[3] = tobf(v.w);
  *(bf16x4*)(d + off) = o;
}

// Projections: N = [q(1024) | k | g | v]; per-segment epilogue. la = RAW
// log-sigmoid (prefix-sum happens in k_transform now).
__global__ __launch_bounds__(256) void k_proj(
    const bf16* __restrict__ hsb,
    const bf16* __restrict__ Wqb, const bf16* __restrict__ Wkb,
    const bf16* __restrict__ Wgb, const bf16* __restrict__ Wvb,
    const float* __restrict__ bq, const float* __restrict__ bk,
    const float* __restrict__ bg, const float* __restrict__ bv,
    bf16* __restrict__ qb, bf16* __restrict__ kb,
    float* __restrict__ la, bf16* __restrict__ vb)
{
  __shared__ __align__(16) bf16 sA[3 * 128 * 32];
  __shared__ __align__(16) bf16 sB[3 * 128 * 32];
  const int m0 = blockIdx.x * 128;
  const int nseg = blockIdx.y;          // 0..31
  const int seg = nseg >> 3;            // 0..3
  const int n0 = (nseg & 7) * 128;      // within segment
  const bf16* W = seg == 0 ? Wqb : seg == 1 ? Wkb : seg == 2 ? Wgb : Wvb;
  const float* bias = seg == 0 ? bq : seg == 1 ? bk : seg == 2 ? bg : bv;
  const int tid = threadIdx.x, lane = tid & 63;
  const int wr = (tid >> 6) >> 1, wc = (tid >> 6) & 1;
  f32x4 acc[16];
#pragma unroll
  for (int i = 0; i < 16; ++i) acc[i] = fzero();
  gemm_core<128, 128>(hsb, H_, m0, W, H_, n0, H_, acc, sA, sB, tid);
#pragma unroll
  for (int m = 0; m < 4; ++m)
#pragma unroll
    for (int n = 0; n < 4; ++n) {
      f32x4 v = acc[m * 4 + n];
      int col = n0 + wc * 64 + n * 16 + (lane & 15);
      float b = bias[col];
#pragma unroll
      for (int r = 0; r < 4; ++r) {
        int row = m0 + wr * 64 + m * 16 + (lane >> 4) * 4 + r;
        float x = v[r] + b;
        size_t o = (size_t)row * KD + col;
        if (seg == 0)      qb[o] = tobf(x);
        else if (seg == 1) kb[o] = tobf(1.f / (1.f + expf(-x)));
        else if (seg == 2) la[o] = fminf(x, 0.f) - log1pf(expf(-fabsf(x)));
        else               vb[o] = tobf(x);
      }
    }
}

// path0: fused within-chunk prefix of log g + decay-weighted operands:
//   qt = q*exp(pref), kt = k*exp(-pref), kbarT[c][kk][t] = k*exp(laC-pref),
//   laC[c][kk] = chunk total.   path1: V^T [c][vv][t].
__global__ __launch_bounds__(256) void k_transform(
    const bf16* __restrict__ qb, const bf16* __restrict__ kb,
    const float* __restrict__ la, const bf16* __restrict__ vb,
    bf16* __restrict__ qt, bf16* __restrict__ kt,
    bf16* __restrict__ kbarT, bf16* __restrict__ vT,
    float* __restrict__ laC)
{
  __shared__ bf16 tr[64][72];
  __shared__ float gtot[4][64];
  const int c = blockIdx.y, tile = blockIdx.x, path = blockIdx.z;
  const int tid = threadIdx.x;
  const int colL = tid & 63;
  const int grp = tid >> 6;            // 0..3
  if (path == 0) {
    const int kk0 = tile * 64;
    const int kk = kk0 + colL;
    float lraw[16];
    float run = 0.f;
#pragma unroll
    for (int i = 0; i < 16; ++i) {
      int t = grp * 16 + i;
      lraw[i] = la[(size_t)(c * CH + t) * KD + kk];
      run += lraw[i];
    }
    gtot[grp][colL] = run;
    __syncthreads();
    float off = 0.f, lc = 0.f;
#pragma unroll
    for (int g2 = 0; g2 < 4; ++g2) {
      float v = gtot[g2][colL];
      if (g2 < grp) off += v;
      lc += v;
    }
    if (grp == 0) laC[(size_t)c * KD + kk] = lc;
    float run2 = off;
#pragma unroll
    for (int i = 0; i < 16; ++i) {
      int t = grp * 16 + i;
      run2 += lraw[i];
      size_t idx = (size_t)(c * CH + t) * KD + kk;
      float qv = (float)qb[idx];
      float kv = (float)kb[idx];
      qt[idx] = tobf(qv * expf(run2));
      kt[idx] = tobf(kv * expf(-run2));
      tr[colL][t] = tobf(kv * expf(lc - run2));   // kbar, staged for transpose
    }
    __syncthreads();
#pragma unroll
    for (int i = 0; i < 16; ++i) {
      int row = grp + 4 * i;
      kbarT[((size_t)c * KD + kk0 + row) * 64 + colL] = tr[row][colL];
    }
  } else {
    const int vv0 = tile * 64;
#pragma unroll
    for (int i = 0; i < 16; ++i) {
      int t = grp + 4 * i;
      tr[colL][t] = vb[(size_t)(c * CH + t) * VD + vv0 + colL];
    }
    __syncthreads();
#pragma unroll
    for (int i = 0; i < 16; ++i) {
      int row = grp + 4 * i;
      vT[((size_t)c * VD + vv0 + row) * 64 + colL] = tr[row][colL];
    }
  }
}

// K-split QK^T partials: Ppart[c][ks] = q~_c K-slice @ k~_c K-slice^T (fp32)
__global__ __launch_bounds__(256) void k_qkt(
    const bf16* __restrict__ qt, const bf16* __restrict__ kt,
    float* __restrict__ Ppart)
{
  __shared__ __align__(16) bf16 sA[3 * 64 * 32];
  __shared__ __align__(16) bf16 sB[3 * 64 * 32];
  const int ks = blockIdx.x, c = blockIdx.y;
  const int tid = threadIdx.x, lane = tid & 63;
  const int wr = (tid >> 6) >> 1, wc = (tid >> 6) & 1;
  f32x4 acc[4];
#pragma unroll
  for (int i = 0; i < 4; ++i) acc[i] = fzero();
  gemm_core<64, 64>(qt + (size_t)c * CH * KD + ks * 256, KD, 0,
                    kt + (size_t)c * CH * KD + ks * 256, KD, 0, 256,
                    acc, sA, sB, tid);
  float* dst = Ppart + ((size_t)c * 4 + ks) * 4096;
#pragma unroll
  for (int m = 0; m < 2; ++m)
#pragma unroll
    for (int n = 0; n < 2; ++n) {
      f32x4 v = acc[m * 2 + n];
      int j = wc * 32 + n * 16 + (lane & 15);
#pragma unroll
      for (int r = 0; r < 4; ++r) {
        int t = wr * 32 + m * 16 + (lane >> 4) * 4 + r;
        dst[t * 64 + j] = v[r];
      }
    }
}

// sum partials -> mask -> P bf16 (LDS) -> PV for a 256-col V slice -> attn
__global__ __launch_bounds__(256) void k_pv(
    const float* __restrict__ Ppart, const bf16* __restrict__ vT,
    float* __restrict__ attn)
{
  __shared__ __align__(16) bf16 Pl[64 * 72];
  __shared__ __align__(16) bf16 sV[128 * 72];
  const int vh = blockIdx.x, c = blockIdx.y;
  const int tid = threadIdx.x, lane = tid & 63;
  const int wr = (tid >> 6) >> 1, wc = (tid >> 6) & 1;
  {
    const float* base = Ppart + (size_t)c * 4 * 4096;
    const int i0 = tid * 16;
    const int t = tid >> 2;
    const int j0 = (tid & 3) * 16;
#pragma unroll
    for (int e = 0; e < 16; e += 4) {
      float4 s0 = *(const float4*)(base + 0 * 4096 + i0 + e);
      float4 s1 = *(const float4*)(base + 1 * 4096 + i0 + e);
      float4 s2 = *(const float4*)(base + 2 * 4096 + i0 + e);
      float4 s3 = *(const float4*)(base + 3 * 4096 + i0 + e);
      float sx = s0.x + s1.x + s2.x + s3.x;
      float sy = s0.y + s1.y + s2.y + s3.y;
      float sz = s0.z + s1.z + s2.z + s3.z;
      float sw = s0.w + s1.w + s2.w + s3.w;
      int j = j0 + e;
      Pl[t * 72 + j + 0] = (j + 0 <= t) ? tobf(sx) : tobf(0.f);
      Pl[t * 72 + j + 1] = (j + 1 <= t) ? tobf(sy) : tobf(0.f);
      Pl[t * 72 + j + 2] = (j + 2 <= t) ? tobf(sz) : tobf(0.f);
      Pl[t * 72 + j + 3] = (j + 3 <= t) ? tobf(sw) : tobf(0.f);
    }
  }
  for (int nb2 = 0; nb2 < 2; ++nb2) {
    const int nb = vh * 2 + nb2;
    __syncthreads();
#pragma unroll
    for (int rr = 0; rr < 4; ++rr) {
      int row = rr * 32 + (tid >> 3);
      int j0 = (tid & 7) * 8;
      bf16x8 vv = *(const bf16x8*)(vT + ((size_t)c * VD + nb * 128 + row) * 64 + j0);
      *(bf16x8*)(sV + row * 72 + j0) = vv;
    }
    __syncthreads();
    f32x4 a2[8];
#pragma unroll
    for (int i = 0; i < 8; ++i) a2[i] = fzero();
#pragma unroll
    for (int ks = 0; ks < 64; ks += 32) {
      bf16x8 af[2], bfr[4];
#pragma unroll
      for (int m = 0; m < 2; ++m)
        af[m] = *(const bf16x8*)(Pl + (wr * 32 + m * 16 + (lane & 15)) * 72
                                 + ks + (lane >> 4) * 8);
#pragma unroll
      for (int n = 0; n < 4; ++n)
        bfr[n] = *(const bf16x8*)(sV + (wc * 64 + n * 16 + (lane & 15)) * 72
                                  + ks + (lane >> 4) * 8);
#pragma unroll
      for (int m = 0; m < 2; ++m)
#pragma unroll
        for (int n = 0; n < 4; ++n)
          a2[m * 4 + n] = __builtin_amdgcn_mfma_f32_16x16x32_bf16(
              af[m], bfr[n], a2[m * 4 + n], 0, 0, 0);
    }
#pragma unroll
    for (int m = 0; m < 2; ++m)
#pragma unroll
      for (int n = 0; n < 4; ++n) {
        int col = wc * 64 + n * 16 + (lane & 15);
#pragma unroll
        for (int r = 0; r < 4; ++r) {
          int row = wr * 32 + m * 16 + (lane >> 4) * 4 + r;
          attn[((size_t)c * CH + row) * VD + nb * 128 + col] = a2[m * 4 + n][r];
        }
      }
  }
}

// U^T[vv][kk] = sum_j V[j,vv] kbar[j,kk]  -> ustore slot (bf16)
__global__ __launch_bounds__(256) void k_ugemm(
    const bf16* __restrict__ vT, const bf16* __restrict__ kbarT,
    bf16* __restrict__ ustore, int g)
{
  __shared__ __align__(16) bf16 sA[3 * 128 * 32];
  __shared__ __align__(16) bf16 sB[3 * 128 * 32];
  const int cl = blockIdx.z, c = g * CPG + cl;
  const int m0 = blockIdx.x * 128, n0 = blockIdx.y * 128;
  const int tid = threadIdx.x, lane = tid & 63;
  const int wr = (tid >> 6) >> 1, wc = (tid >> 6) & 1;
  f32x4 acc[16];
#pragma unroll
  for (int i = 0; i < 16; ++i) acc[i] = fzero();
  gemm_core<128, 128>(vT + (size_t)c * VD * 64, 64, m0,
                      kbarT + (size_t)c * KD * 64, 64, n0, 64, acc, sA, sB, tid);
  bf16* dst = ustore + (size_t)cl * KD * VD;
#pragma unroll
  for (int m = 0; m < 4; ++m)
#pragma unroll
    for (int n = 0; n < 4; ++n) {
      f32x4 v = acc[m * 4 + n];
      int col = wc * 64 + n * 16 + (lane & 15);
#pragma unroll
      for (int r = 0; r < 4; ++r) {
        int row = wr * 64 + m * 16 + (lane >> 4) * 4 + r;
        dst[(size_t)(m0 + row) * KD + n0 + col] = tobf(v[r]);
      }
    }
}

// elementwise scan over chunks — vectorized bf16x8 (8 kk per thread)
__global__ __launch_bounds__(256) void k_scan(
    bf16* __restrict__ ustore, const float* __restrict__ laC,
    float* __restrict__ Sinit, bf16* __restrict__ ScarryB,
    float* __restrict__ dstate, int g)
{
  __shared__ float tl[64][132];
  const int vv0 = blockIdx.x * 64, kk0 = blockIdx.y * 128;
  const int tid = threadIdx.x;
  const int kv = (tid & 15) * 8;
  const int vr = tid >> 4;
  float s[4][8];
  if (g == 0) {
#pragma unroll
    for (int i = 0; i < 4; ++i)
#pragma unroll
      for (int j = 0; j < 8; ++j) s[i][j] = 0.f;
  } else {
#pragma unroll
    for (int i = 0; i < 4; ++i) {
      const float* p = Sinit + (size_t)(vv0 + vr + 16 * i) * KD + kk0 + kv;
      float4 a = *(const float4*)p, b = *(const float4*)(p + 4);
      s[i][0]=a.x; s[i][1]=a.y; s[i][2]=a.z; s[i][3]=a.w;
      s[i][4]=b.x; s[i][5]=b.y; s[i][6]=b.z; s[i][7]=b.w;
    }
  }
  for (int cl = 0; cl < CPG; ++cl) {
    int c = g * CPG + cl;
    const float* lp = laC + (size_t)c * KD + kk0 + kv;
    float4 la0 = *(const float4*)lp, la1 = *(const float4*)(lp + 4);
    float d[8] = {expf(la0.x), expf(la0.y), expf(la0.z), expf(la0.w),
                  expf(la1.x), expf(la1.y), expf(la1.z), expf(la1.w)};
    size_t base = (size_t)cl * KD * VD;
#pragma unroll
    for (int i = 0; i < 4; ++i) {
      bf16* up = ustore + base + (size_t)(vv0 + vr + 16 * i) * KD + kk0 + kv;
      bf16x8 u = *(const bf16x8*)up;
      bf16x8 o;
#pragma unroll
      for (int j = 0; j < 8; ++j) {
        s[i][j] = fmaf(d[j], s[i][j], (float)u[j]);
        o[j] = tobf(s[i][j]);
      }
      *(bf16x8*)up = o;
    }
  }
  if (g < NGROUP - 1) {
#pragma unroll
    for (int i = 0; i < 4; ++i) {
      float* p = Sinit + (size_t)(vv0 + vr + 16 * i) * KD + kk0 + kv;
      bf16* pb = ScarryB + (size_t)(vv0 + vr + 16 * i) * KD + kk0 + kv;
      float4 a = {s[i][0], s[i][1], s[i][2], s[i][3]};
      float4 b = {s[i][4], s[i][5], s[i][6], s[i][7]};
      *(float4*)p = a; *(float4*)(p + 4) = b;
      bf16x8 o;
#pragma unroll
      for (int j = 0; j < 8; ++j) o[j] = tobf(s[i][j]);
      *(bf16x8*)pb = o;
    }
  } else {
#pragma unroll
    for (int i = 0; i < 4; ++i)
#pragma unroll
      for (int j = 0; j < 8; ++j) tl[vr + 16 * i][kv + j] = s[i][j];
    __syncthreads();
    const int kkL = tid >> 1;
    const int vvh = (tid & 1) * 32;
    float* dp = dstate + (size_t)(kk0 + kkL) * VD + vv0 + vvh;
#pragma unroll
    for (int j4 = 0; j4 < 8; ++j4) {
      float4 o2 = {tl[vvh + j4 * 4 + 0][kkL], tl[vvh + j4 * 4 + 1][kkL],
                   tl[vvh + j4 * 4 + 2][kkL], tl[vvh + j4 * 4 + 3][kkL]};
      *(float4*)(dp + j4 * 4) = o2;
    }
  }
}

// out_inter = q~_c @ S_{c-1}; fused: ob = bf16(attn_intra + inter)
__global__ __launch_bounds__(256) void k_inter(
    const bf16* __restrict__ qt, const bf16* __restrict__ ustore,
    const bf16* __restrict__ ScarryB, const float* __restrict__ attn,
    bf16* __restrict__ ob, int g)
{
  const int cl = blockIdx.y, c = g * CPG + cl;
  const int n0 = blockIdx.x * 128;
  const int tid = threadIdx.x;
  if (c == 0) {
    // chunk 0 has no inter term: convert intra result only
    for (int i = tid; i < (64 * 128) / 4; i += 256) {
      int idx = i * 4;
      int r = idx >> 7, c2 = idx & 127;
      float4 v = *(const float4*)(attn + (size_t)r * VD + n0 + c2);
      bf16x4 o; o[0]=tobf(v.x); o[1]=tobf(v.y); o[2]=tobf(v.z); o[3]=tobf(v.w);
      *(bf16x4*)(ob + (size_t)r * VD + n0 + c2) = o;
    }
    return;
  }
  __shared__ __align__(16) bf16 sA[3 * 64 * 32];
  __shared__ __align__(16) bf16 sB[3 * 128 * 32];
  const bf16* B = (cl == 0) ? ScarryB : ustore + (size_t)(cl - 1) * KD * VD;
  const int lane = tid & 63;
  const int wr = (tid >> 6) >> 1, wc = (tid >> 6) & 1;
  f32x4 acc[8];
#pragma unroll
  for (int i = 0; i < 8; ++i) acc[i] = fzero();
  gemm_core<64, 128>(qt + (size_t)c * CH * KD, KD, 0, B, KD, n0, KD,
                     acc, sA, sB, tid);
#pragma unroll
  for (int m = 0; m < 2; ++m)
#pragma unroll
    for (int n = 0; n < 4; ++n) {
      f32x4 v = acc[m * 4 + n];
      int col = wc * 64 + n * 16 + (lane & 15);
#pragma unroll
      for (int r = 0; r < 4; ++r) {
        int row = wr * 32 + m * 16 + (lane >> 4) * 4 + r;
        size_t o = ((size_t)c * CH + row) * VD + n0 + col;
        ob[o] = tobf(attn[o] + v[r]);
      }
    }
}

// y = ob @ Wo^T + bo
__global__ __launch_bounds__(256) void k_out(
    const bf16* __restrict__ ob, const bf16* __restrict__ Wob,
    const float* __restrict__ bo, float* __restrict__ out)
{
  __shared__ __align__(16) bf16 sA[3 * 128 * 32];
  __shared__ __align__(16) bf16 sB[3 * 128 * 32];
  const int m0 = blockIdx.x * 128, n0 = blockIdx.y * 128;
  const int tid = threadIdx.x, lane = tid & 63;
  const int wr = (tid >> 6) >> 1, wc = (tid >> 6) & 1;
  f32x4 acc[16];
#pragma unroll
  for (int i = 0; i < 16; ++i) acc[i] = fzero();
  gemm_core<128, 128>(ob, VD, m0, Wob, VD, n0, VD, acc, sA, sB, tid);
#pragma unroll
  for (int m = 0; m < 4; ++m)
#pragma unroll
    for (int n = 0; n < 4; ++n) {
      f32x4 v = acc[m * 4 + n];
      int col = n0 + wc * 64 + n * 16 + (lane & 15);
      float b = bo[col];
#pragma unroll
      for (int r = 0; r < 4; ++r) {
        int row = m0 + wr * 64 + m * 16 + (lane >> 4) * 4 + r;
        out[(size_t)row * OD + col] = v[r] + b;
      }
    }
}

// ---------------------------------------------------------------------------
extern "C" void kernel_launch(void* const* d_in, const int* in_sizes, int n_in,
                              void* d_out, int out_size, void* d_ws, size_t ws_size,
                              hipStream_t stream)
{
  const float* hs = (const float*)d_in[0];
  const float* Wq = (const float*)d_in[1];
  const float* bq = (const float*)d_in[2];
  const float* Wk = (const float*)d_in[3];
  const float* bk = (const float*)d_in[4];
  const float* Wv = (const float*)d_in[5];
  const float* bv = (const float*)d_in[6];
  const float* Wg = (const float*)d_in[7];
  const float* bg = (const float*)d_in[8];
  const float* Wo = (const float*)d_in[9];
  const float* bo = (const float*)d_in[10];
  float* out = (float*)d_out;
  float* dstate = out + (size_t)T_ * OD;

  char* p = (char*)d_ws;
  auto alloc = [&](size_t b) -> char* {
    char* r = p; p += (b + 255) & ~(size_t)255; return r;
  };
  bf16* hsb    = (bf16*)alloc((size_t)T_ * H_ * 2);
  bf16* Wqb    = (bf16*)alloc((size_t)KD * H_ * 2);
  bf16* Wkb    = (bf16*)alloc((size_t)KD * H_ * 2);
  bf16* Wgb    = (bf16*)alloc((size_t)KD * H_ * 2);
  bf16* Wvb    = (bf16*)alloc((size_t)VD * H_ * 2);
  bf16* Wob    = (bf16*)alloc((size_t)OD * VD * 2);
  bf16* qb     = (bf16*)alloc((size_t)T_ * KD * 2);
  bf16* kb     = (bf16*)alloc((size_t)T_ * KD * 2);
  float* la    = (float*)alloc((size_t)T_ * KD * 4);
  bf16* vb     = (bf16*)alloc((size_t)T_ * VD * 2);
  bf16* qt     = (bf16*)alloc((size_t)T_ * KD * 2);
  bf16* kt     = (bf16*)alloc((size_t)T_ * KD * 2);
  bf16* kbarT  = (bf16*)alloc((size_t)T_ * KD * 2);
  bf16* vT     = (bf16*)alloc((size_t)T_ * VD * 2);
  float* attn  = (float*)alloc((size_t)T_ * VD * 4);
  bf16* ob     = (bf16*)alloc((size_t)T_ * VD * 2);
  float* Sinit = (float*)alloc((size_t)KD * VD * 4);
  bf16* ScarryB= (bf16*)alloc((size_t)KD * VD * 2);
  bf16* ustore = (bf16*)alloc((size_t)CPG * KD * VD * 2);
  float* laC   = (float*)alloc((size_t)NCHUNK * KD * 4);
  float* Ppart = (float*)alloc((size_t)NCHUNK * 4 * 4096 * 4);
  if ((size_t)(p - (char*)d_ws) > ws_size) return;

  k_cvt6<<<(int)((CVT_TOT / 4 + 255) / 256), 256, 0, stream>>>(
      hs, Wq, Wk, Wg, Wv, Wo, hsb, Wqb, Wkb, Wgb, Wvb, Wob);

  k_proj<<<dim3(T_ / 128, 32), 256, 0, stream>>>(
      hsb, Wqb, Wkb, Wgb, Wvb, bq, bk, bg, bv, qb, kb, la, vb);

  // fused cumsum + decay transforms + transposes
  k_transform<<<dim3(16, NCHUNK, 2), 256, 0, stream>>>(
      qb, kb, la, vb, qt, kt, kbarT, vT, laC);

  // intra-chunk attention, split for full-GPU grids
  k_qkt<<<dim3(4, NCHUNK), 256, 0, stream>>>(qt, kt, Ppart);
  k_pv<<<dim3(4, NCHUNK), 256, 0, stream>>>(Ppart, vT, attn);

  for (int g = 0; g < NGROUP; ++g) {
    k_ugemm<<<dim3(8, 8, CPG), 256, 0, stream>>>(vT, kbarT, ustore, g);
    k_scan<<<dim3(16, 8), 256, 0, stream>>>(ustore, laC, Sinit, ScarryB, dstate, g);
    k_inter<<<dim3(8, CPG), 256, 0, stream>>>(qt, ustore, ScarryB, attn, ob, g);
  }

  k_out<<<dim3(T_ / 128, OD / 128), 256, 0, stream>>>(ob, Wob, bo, out);
}